// Round 2
// baseline (455.317 us; speedup 1.0000x reference)
//
#include <hip/hip_runtime.h>
#include <math.h>

#define THREADS 256
#define SORTT 1024

// ---------------- problem constants (fixed by reference setup) ----------------
constexpr int NLEV  = 5;
constexpr int NB    = 16;     // batch
constexpr int NC    = 80;     // classes (label = c+1)
constexpr int TOPN  = 300;
constexpr int KC    = NLEV * TOPN;   // 1500 candidates per image
constexpr int KROWS = 1536;          // padded rows for NMS bitmask
constexpr int WORDS = 24;            // 1536 / 64
constexpr int POSTN = 100;
constexpr int CAP   = 4096;          // per-(b,level) candidate pool
constexpr int NBINS = 2048;          // score-histogram bins over [0.25, 1.0)
constexpr int NPAIR = NLEV * NB;     // 80

constexpr int HW0 = 12800, HW1 = 3200, HW2 = 800, HW3 = 208, HW4 = 56;
constexpr int CH0 = 63, CH1 = 16, CH2 = 4, CH3 = 2, CH4 = 1;  // 16384-elem chunks per (b,level)
constexpr int CHUNKS = CH0 + CH1 + CH2 + CH3 + CH4;           // 86

// sigmoid(ctr) precompute: per-level bases into sct[] (floats), layout [li][b][hw]
constexpr int SCTB0 = 0;
constexpr int SCTB1 = 204800;
constexpr int SCTB2 = 256000;
constexpr int SCTB3 = 268800;
constexpr int SCTB4 = 272128;
constexpr int SCTN  = 273024;

// group-max skip list: 256-element groups, layout [li][b][g] (u16)
constexpr int GPL0 = 4000, GPL1 = 1000, GPL2 = 250, GPL3 = 65, GPL4 = 18;
constexpr int GMXB0 = 0;
constexpr int GMXB1 = GMXB0 + NB * GPL0;
constexpr int GMXB2 = GMXB1 + NB * GPL1;
constexpr int GMXB3 = GMXB2 + NB * GPL2;
constexpr int GMXB4 = GMXB3 + NB * GPL3;
constexpr int GMXN  = GMXB4 + NB * GPL4;

constexpr int GLCAP = 96 * 1024;    // global passing-group list capacity (worst case 85,328)

// ---------------- workspace layout ----------------
constexpr size_t align256(size_t x) { return (x + 255) & ~(size_t)255; }
constexpr size_t OFF_HIST = 0;
constexpr size_t OFF_CNT  = OFF_HIST + (size_t)NPAIR * NBINS * 4;
constexpr size_t OFF_CAND = align256(OFF_CNT + (size_t)NPAIR * 4);
constexpr size_t OFF_CBOX = align256(OFF_CAND + (size_t)NPAIR * CAP * 8);
constexpr size_t OFF_CSC  = align256(OFF_CBOX + (size_t)NB * KC * 4 * 4);
constexpr size_t OFF_CLB  = align256(OFF_CSC  + (size_t)NB * KC * 4);
constexpr size_t OFF_SSC  = align256(OFF_CLB  + (size_t)NB * KC * 4);
constexpr size_t OFF_SLB  = align256(OFF_SSC  + (size_t)NB * KC * 4);
constexpr size_t OFF_SBOX = align256(OFF_SLB  + (size_t)NB * KC * 4);
constexpr size_t OFF_OBOX = align256(OFF_SBOX + (size_t)NB * KC * 4 * 4);
constexpr size_t OFF_M    = align256(OFF_OBOX + (size_t)NB * KC * 4 * 4);
constexpr size_t OFF_SCT  = align256(OFF_M + (size_t)NB * KROWS * WORDS * 8);
constexpr size_t OFF_GMX  = align256(OFF_SCT + (size_t)SCTN * 4);
constexpr size_t OFF_TV   = align256(OFF_GMX + (size_t)GMXN * 2);    // NPAIR thresholds (u32)
constexpr size_t OFF_GCNT = align256(OFF_TV + (size_t)NPAIR * 4);    // 1 u32 work-list count
constexpr size_t OFF_GL   = align256(OFF_GCNT + 256);                // GLCAP u32 entries
// total ~16.3 MB

struct Cand { float s; int i; };

// ---------------- helpers ----------------
__device__ __forceinline__ float sigm(float x) { return 1.0f / (1.0f + expf(-x)); }

// fast sigmoid (hw v_exp_f32 + v_rcp_f32, <=~4 ulp). Used ONLY for the histogram /
// skip-list (threshold selection): |approx key - exact key| <= 1 bin, compensated
// by collecting key >= TA-1 and gating groups by gmx+1 >= Tv. Collect/select use
// the exact sigm() so the final output is bit-identical.
__device__ __forceinline__ float sigf(float x) {
#if __has_builtin(__builtin_amdgcn_exp2f) && __has_builtin(__builtin_amdgcn_rcpf)
    float e = __builtin_amdgcn_exp2f(__fmul_rn(x, -1.44269504088896340736f));
    return __builtin_amdgcn_rcpf(__fadd_rn(1.0f, e));
#else
    return 1.0f / (1.0f + __expf(-x));
#endif
}

// monotone key over score in (0,1): 2048 bins over [0.25,1.0), everything below -> bin 0
__device__ __forceinline__ unsigned scoreKey(float s) {
    unsigned b = __float_as_uint(s);
    unsigned k = (b < 0x3E800000u) ? 0u : ((b - 0x3E800000u) >> 13);
    return (k > 2047u) ? 2047u : k;
}

__device__ __forceinline__ unsigned long long readlane64(unsigned long long v, int l) {
    unsigned lo = (unsigned)__builtin_amdgcn_readlane((int)(unsigned)(v & 0xffffffffull), l);
    unsigned hi = (unsigned)__builtin_amdgcn_readlane((int)(unsigned)(v >> 32), l);
    return ((unsigned long long)hi << 32) | lo;
}

// exact comparator shared by select/sort ranking: score desc, candidate-idx asc
__device__ __forceinline__ int cmpBefore(float sj, int ij, float sk, int ik) {
    return (sj > sk) || (sj == sk && ij < ik);
}

// ---------------- K0: fused zero (hist+cnt+gcount) + sigmoid(ctr) precompute ----------------
__global__ __launch_bounds__(THREADS) void k_init(
        const float* t0, const float* t1, const float* t2, const float* t3, const float* t4,
        float* __restrict__ sct, unsigned* __restrict__ zp, int zn, unsigned* __restrict__ gcount) {
    int i = blockIdx.x * THREADS + threadIdx.x;
    if (i == 0) *gcount = 0;
    if (i < zn) zp[i] = 0;
    if (i < SCTN) {
        float x;
        if (i < SCTB1)      x = t0[i - SCTB0];
        else if (i < SCTB2) x = t1[i - SCTB1];
        else if (i < SCTB3) x = t2[i - SCTB2];
        else if (i < SCTB4) x = t3[i - SCTB3];
        else                x = t4[i - SCTB4];
        sct[i] = sigm(x);   // exact: same formula as reference sigmoid usage
    }
}

// ---------------- K1: approx histogram + per-256-group max approx key ----------------
template<int HW, int SCTB, int GPL, int GMXB>
__device__ __forceinline__ void histChunkV(int chunkLocal, int b,
        const float* __restrict__ cls, const float* __restrict__ sct,
        unsigned short* __restrict__ gmx, unsigned* __restrict__ h) {
    constexpr int NE = HW * NC;
    const float* cp = cls + (size_t)b * NE;
    const float* tb = sct + SCTB + b * HW;
    unsigned short* gp = gmx + GMXB + (size_t)b * GPL;
    int w = threadIdx.x >> 6, lane = threadIdx.x & 63;
    int half = lane >> 5, hlane = lane & 31;
    for (int bi = w; bi < 32; bi += 4) {
        int ebase = (chunkLocal * 32 + bi) * 512;
        if (ebase >= NE) break;
        int e = ebase + lane * 8;
        int kmax = 0;
        if (e < NE) {   // NE%8==0 -> e<NE implies e+7<NE
            int c = e / HW; int hwb = e - c * HW;
            float4 xa = *(const float4*)(cp + e);
            float4 xb = *(const float4*)(cp + e + 4);
            float4 ta = *(const float4*)(tb + hwb);
            float4 tc = *(const float4*)(tb + hwb + 4);
            float xs[8] = {xa.x, xa.y, xa.z, xa.w, xb.x, xb.y, xb.z, xb.w};
            float ts[8] = {ta.x, ta.y, ta.z, ta.w, tc.x, tc.y, tc.z, tc.w};
            #pragma unroll
            for (int q = 0; q < 8; ++q) {
                float scls = sigf(xs[q]);                // FAST sigmoid (approx key)
                float s = __fmul_rn(scls, ts[q]);
                unsigned key = scoreKey(s);
                if (key) atomicAdd(&h[key], 1u);
                kmax = max(kmax, (int)key);
            }
        }
        #pragma unroll
        for (int sh = 1; sh < 32; sh <<= 1) kmax = max(kmax, __shfl_xor(kmax, sh, 64));
        int g = (ebase >> 8) + half;
        if (hlane == 0 && g * 256 < NE) gp[g] = (unsigned short)kmax;
    }
}

__global__ __launch_bounds__(THREADS) void k_hist(
        const float* c0, const float* c1, const float* c2, const float* c3, const float* c4,
        const float* __restrict__ sct, unsigned short* __restrict__ gmx, unsigned* ghist) {
    __shared__ unsigned h[NBINS];
    for (int k = threadIdx.x; k < NBINS; k += THREADS) h[k] = 0;
    __syncthreads();
    int cx = blockIdx.x, b = blockIdx.y;
    int li;
    if (cx < CH0)                 { histChunkV<HW0,SCTB0,GPL0,GMXB0>(cx, b, c0, sct, gmx, h); li = 0; }
    else if (cx < CH0+CH1)        { histChunkV<HW1,SCTB1,GPL1,GMXB1>(cx-CH0, b, c1, sct, gmx, h); li = 1; }
    else if (cx < CH0+CH1+CH2)    { histChunkV<HW2,SCTB2,GPL2,GMXB2>(cx-CH0-CH1, b, c2, sct, gmx, h); li = 2; }
    else if (cx < CH0+CH1+CH2+CH3){ histChunkV<HW3,SCTB3,GPL3,GMXB3>(cx-CH0-CH1-CH2, b, c3, sct, gmx, h); li = 3; }
    else                          { histChunkV<HW4,SCTB4,GPL4,GMXB4>(cx-CH0-CH1-CH2-CH3, b, c4, sct, gmx, h); li = 4; }
    __syncthreads();
    unsigned* gp = ghist + (size_t)(li * NB + b) * NBINS;
    for (int k = threadIdx.x; k < NBINS; k += THREADS) {
        unsigned v = h[k];
        if (v) atomicAdd(&gp[k], v);
    }
}

// ---------------- K2: per-(li,b) threshold + GLOBAL passing-group work-list ----------
// One block per pid: computes Tv (identical math to before), then scans this pid's
// group-max array and ballot-compacts passing groups into one global list that
// k_collect grid-strides over. Removes the per-block gmx prologue and the ~95%
// idle blocks from the old 1376-block k_collect.
__global__ __launch_bounds__(THREADS) void k_thresh(
        const unsigned* __restrict__ ghist, const unsigned short* __restrict__ gmx,
        unsigned* __restrict__ tvs, unsigned* __restrict__ gcount, unsigned* __restrict__ glist) {
    __shared__ unsigned seg[THREADS];
    __shared__ unsigned shTv;
    int pid = blockIdx.x;
    int li = pid >> 4, b = pid & 15;
    const unsigned* h = ghist + (size_t)pid * NBINS;
    constexpr int SB = NBINS / THREADS;   // 8
    unsigned s = 0;
    for (int k = 0; k < SB; ++k) s += h[threadIdx.x * SB + k];
    seg[threadIdx.x] = s;
    __syncthreads();
    if (threadIdx.x == 0) {
        unsigned acc = 0; unsigned TA = 0;
        int t = THREADS - 1;
        for (; t >= 0; --t) {
            if (acc + seg[t] >= (unsigned)TOPN) break;
            acc += seg[t];
        }
        if (t >= 0) {
            int lo = t * SB;
            int bin = lo + SB - 1;
            for (; bin >= lo; --bin) { acc += h[bin]; if (acc >= (unsigned)TOPN) break; }
            TA = (unsigned)max(bin, lo);
        }
        unsigned Tv = (TA >= 1) ? (TA - 1) : 0;   // 0 => degenerate fallback
        shTv = Tv;
        tvs[pid] = Tv;
    }
    __syncthreads();
    unsigned Tv = shTv;
    int GPL, GMXB;
    switch (li) {
        case 0: GPL = GPL0; GMXB = GMXB0; break;
        case 1: GPL = GPL1; GMXB = GMXB1; break;
        case 2: GPL = GPL2; GMXB = GMXB2; break;
        case 3: GPL = GPL3; GMXB = GMXB3; break;
        default: GPL = GPL4; GMXB = GMXB4; break;
    }
    const unsigned short* gp = gmx + GMXB + (size_t)b * GPL;
    for (int g0 = 0; g0 < GPL; g0 += THREADS) {
        int g = g0 + (int)threadIdx.x;
        bool ok = (g < GPL);
        if (ok && Tv) ok = ((unsigned)gp[g] + 1u >= Tv);   // gmx is max APPROX key: +1 slack
        unsigned long long m = __ballot(ok);
        int nW = __popcll(m);
        if (nW) {
            unsigned base = 0;
            if ((threadIdx.x & 63) == 0) base = atomicAdd(gcount, (unsigned)nW);
            base = (unsigned)__builtin_amdgcn_readfirstlane((int)base);
            if (ok) {
                unsigned slot = base + (unsigned)__popcll(m & ((1ull << (threadIdx.x & 63)) - 1ull));
                if (slot < (unsigned)GLCAP) glist[slot] = ((unsigned)pid << 12) | (unsigned)g;
            }
        }
    }
}

// ---------------- K3: work-list-driven compaction (256 threads = 1 group / iter) ----
template<int HW, int SCTB>
__device__ __forceinline__ void procGroup(int g, int b, int pid, unsigned Tv,
        const float* __restrict__ cls, const float* __restrict__ sct,
        Cand* __restrict__ cd, unsigned* __restrict__ cnt) {
    constexpr int NE = HW * NC;
    const float* cp = cls + (size_t)b * NE;
    const float* tb = sct + SCTB + b * HW;
    int e = g * 256 + (int)threadIdx.x;
    bool ok = (e < NE);
    int ee = ok ? e : 0;
    int c = ee / HW; int hw = ee - c * HW;
    float x = cp[ee];
    float t = tb[hw];
    float scls = sigm(x);                 // EXACT sigmoid for stored score
    float s = __fmul_rn(scls, t);
    unsigned key = scoreKey(s);
    bool take = ok && (Tv ? (key >= Tv) : (scls > 0.05f));
    unsigned long long m = __ballot(take);
    int nW = __popcll(m);
    if (nW) {
        unsigned base = 0;
        if ((threadIdx.x & 63) == 0) base = atomicAdd(&cnt[pid], (unsigned)nW);
        base = (unsigned)__builtin_amdgcn_readfirstlane((int)base);
        if (take) {
            unsigned slot = base + (unsigned)__popcll(m & ((1ull << (threadIdx.x & 63)) - 1ull));
            if (slot < (unsigned)CAP) { cd[slot].s = s; cd[slot].i = hw * NC + c; }
        }
    }
}

__global__ __launch_bounds__(THREADS) void k_collect(
        const float* c0, const float* c1, const float* c2, const float* c3, const float* c4,
        const float* __restrict__ sct, const unsigned* __restrict__ tvs,
        const unsigned* __restrict__ gcount, const unsigned* __restrict__ glist,
        Cand* cand, unsigned* cnt) {
    unsigned n = *gcount;
    if (n > (unsigned)GLCAP) n = GLCAP;
    for (unsigned gi = blockIdx.x; gi < n; gi += gridDim.x) {
        unsigned entry = glist[gi];
        int pid = (int)(entry >> 12);
        int g = (int)(entry & 4095u);
        int li = pid >> 4, b = pid & 15;
        unsigned Tv = tvs[pid];
        Cand* cd = cand + (size_t)pid * CAP;
        switch (li) {
            case 0: procGroup<HW0,SCTB0>(g, b, pid, Tv, c0, sct, cd, cnt); break;
            case 1: procGroup<HW1,SCTB1>(g, b, pid, Tv, c1, sct, cd, cnt); break;
            case 2: procGroup<HW2,SCTB2>(g, b, pid, Tv, c2, sct, cd, cnt); break;
            case 3: procGroup<HW3,SCTB3>(g, b, pid, Tv, c3, sct, cd, cnt); break;
            default: procGroup<HW4,SCTB4>(g, b, pid, Tv, c4, sct, cd, cnt); break;
        }
    }
}

// ---------------- K4: exact top-300 per (b,level) via pairwise rank + decode ----------
// Rank r_i = #{j : s_j > s_i || (s_j==s_i && idx_j < idx_i)} — exact sorted position
// with the SAME comparator the old bitonic used. No barrier phases; LDS reads are
// wave-uniform broadcasts batched 4-wide (b128).
__global__ __launch_bounds__(THREADS) void k_select(
        const Cand* __restrict__ candAll, const unsigned* __restrict__ cntAll,
        const float* l0, const float* l1, const float* l2, const float* l3, const float* l4,
        const float* b0, const float* b1, const float* b2, const float* b3, const float* b4,
        float* __restrict__ cbox, float* __restrict__ csc, int* __restrict__ clb) {
    __shared__ __align__(16) float ss[CAP + 4];
    __shared__ __align__(16) int si[CAP + 4];
    int pid = blockIdx.x;
    int li = pid >> 4, b = pid & 15;
    int n = (int)min(cntAll[pid], (unsigned)CAP);
    int npad = (n + 3) & ~3;
    const Cand* cd = candAll + (size_t)pid * CAP;
    for (int k = threadIdx.x; k < npad; k += THREADS) {
        if (k < n) { ss[k] = cd[k].s; si[k] = cd[k].i; }
        else       { ss[k] = -INFINITY; si[k] = 0x7fffffff; }
    }
    __syncthreads();

    const float* locp; const float* boxp; int HW;
    switch (li) {
        case 0: locp = l0; boxp = b0; HW = HW0; break;
        case 1: locp = l1; boxp = b1; HW = HW1; break;
        case 2: locp = l2; boxp = b2; HW = HW2; break;
        case 3: locp = l3; boxp = b3; HW = HW3; break;
        default: locp = l4; boxp = b4; HW = HW4; break;
    }

    // slots beyond the candidate count are invalid
    for (int j = n + (int)threadIdx.x; j < TOPN; j += THREADS) {
        int cidx = b * KC + li * TOPN + j;
        cbox[cidx * 4 + 0] = 0.0f; cbox[cidx * 4 + 1] = 0.0f;
        cbox[cidx * 4 + 2] = 0.0f; cbox[cidx * 4 + 3] = 0.0f;
        csc[cidx] = -INFINITY;
        clb[cidx] = 0;
    }

    for (int k0 = 0; k0 < n; k0 += THREADS * 4) {
        int kA = k0 + (int)threadIdx.x;
        int kB = kA + THREADS, kC2 = kA + 2 * THREADS, kD = kA + 3 * THREADS;
        float sA = (kA < n) ? ss[kA] : 0.0f; int iA = (kA < n) ? si[kA] : 0;
        float sB = (kB < n) ? ss[kB] : 0.0f; int iB = (kB < n) ? si[kB] : 0;
        float sC = (kC2 < n) ? ss[kC2] : 0.0f; int iC = (kC2 < n) ? si[kC2] : 0;
        float sD = (kD < n) ? ss[kD] : 0.0f; int iD = (kD < n) ? si[kD] : 0;
        int rA = 0, rB = 0, rC = 0, rD = 0;
        for (int j = 0; j < npad; j += 4) {
            float4 v = *(const float4*)&ss[j];
            int4 w = *(const int4*)&si[j];
            rA += cmpBefore(v.x, w.x, sA, iA) + cmpBefore(v.y, w.y, sA, iA)
                + cmpBefore(v.z, w.z, sA, iA) + cmpBefore(v.w, w.w, sA, iA);
            rB += cmpBefore(v.x, w.x, sB, iB) + cmpBefore(v.y, w.y, sB, iB)
                + cmpBefore(v.z, w.z, sB, iB) + cmpBefore(v.w, w.w, sB, iB);
            rC += cmpBefore(v.x, w.x, sC, iC) + cmpBefore(v.y, w.y, sC, iC)
                + cmpBefore(v.z, w.z, sC, iC) + cmpBefore(v.w, w.w, sC, iC);
            rD += cmpBefore(v.x, w.x, sD, iD) + cmpBefore(v.y, w.y, sD, iD)
                + cmpBefore(v.z, w.z, sD, iD) + cmpBefore(v.w, w.w, sD, iD);
        }
        #pragma unroll
        for (int q = 0; q < 4; ++q) {
            int k = kA + q * THREADS;
            int r = (q == 0) ? rA : (q == 1) ? rB : (q == 2) ? rC : rD;
            float s = (q == 0) ? sA : (q == 1) ? sB : (q == 2) ? sC : sD;
            int idx = (q == 0) ? iA : (q == 1) ? iB : (q == 2) ? iC : iD;
            if (k < n && r < TOPN) {
                int cidx = b * KC + li * TOPN + r;
                int hw = idx / NC, c = idx - hw * NC;
                float lx = locp[hw * 2 + 0], ly = locp[hw * 2 + 1];
                const float* bp = boxp + (size_t)b * 4 * HW + hw;
                float bl = bp[0], bt = bp[HW], br = bp[2 * HW], bb = bp[3 * HW];
                float x1 = fminf(fmaxf(__fsub_rn(lx, bl), 0.0f), 1023.0f);
                float y1 = fminf(fmaxf(__fsub_rn(ly, bt), 0.0f),  799.0f);
                float x2 = fminf(fmaxf(__fadd_rn(lx, br), 0.0f), 1023.0f);
                float y2 = fminf(fmaxf(__fadd_rn(ly, bb), 0.0f),  799.0f);
                cbox[cidx * 4 + 0] = x1; cbox[cidx * 4 + 1] = y1;
                cbox[cidx * 4 + 2] = x2; cbox[cidx * 4 + 3] = y2;
                csc[cidx] = sqrtf(fmaxf(s, 1e-12f));
                clb[cidx] = c + 1;
            }
        }
    }
}

// ---------------- K5a: per-image order by pairwise rank (stable, matches argsort(-s)) --
__global__ __launch_bounds__(SORTT) void k_sortimg(
        const float* __restrict__ csc, const int* __restrict__ clb, const float* __restrict__ cbox,
        float* __restrict__ ssc, int* __restrict__ slb, float* __restrict__ sbox, float* __restrict__ obox) {
    int b = blockIdx.x;
    __shared__ __align__(16) float ss[1504];
    for (int k = threadIdx.x; k < 1504; k += SORTT)
        ss[k] = (k < KC) ? csc[b * KC + k] : -INFINITY;
    __syncthreads();
    int k1 = (int)threadIdx.x;           // < 1024 < KC, always valid
    int k2 = k1 + SORTT;                 // valid if < KC
    float s1 = ss[k1];
    float s2 = (k2 < KC) ? ss[k2] : 0.0f;
    int r1 = 0, r2 = 0;
    for (int j = 0; j < 1504; j += 4) {
        float4 v = *(const float4*)&ss[j];
        r1 += ((v.x > s1) || (v.x == s1 && (j + 0) < k1))
            + ((v.y > s1) || (v.y == s1 && (j + 1) < k1))
            + ((v.z > s1) || (v.z == s1 && (j + 2) < k1))
            + ((v.w > s1) || (v.w == s1 && (j + 3) < k1));
        r2 += ((v.x > s2) || (v.x == s2 && (j + 0) < k2))
            + ((v.y > s2) || (v.y == s2 && (j + 1) < k2))
            + ((v.z > s2) || (v.z == s2 && (j + 2) < k2))
            + ((v.w > s2) || (v.w == s2 && (j + 3) < k2));
    }
    #pragma unroll
    for (int q = 0; q < 2; ++q) {
        int k = (q == 0) ? k1 : k2;
        int r = (q == 0) ? r1 : r2;
        if (k < KC) {
            int src = b * KC + k, dst = b * KC + r;
            float sc = ss[k];
            int lab = clb[src];
            ssc[dst] = sc; slb[dst] = lab;
            float off = __fmul_rn((float)lab, 1025.0f);   // offset = max(800,1024)+1
            float4 v = *(const float4*)&cbox[(size_t)src * 4];
            *(float4*)&sbox[(size_t)dst * 4] = v;
            float4 o;
            o.x = __fadd_rn(v.x, off); o.y = __fadd_rn(v.y, off);
            o.z = __fadd_rn(v.z, off); o.w = __fadd_rn(v.w, off);
            *(float4*)&obox[(size_t)dst * 4] = o;
        }
    }
}

// ---------------- K5b: suppression bitmask (iou > 0.6 && j > i) ----------------
__global__ __launch_bounds__(64) void k_iou(const float* __restrict__ obox,
                                            unsigned long long* __restrict__ MT) {
    int w = blockIdx.x, tile = blockIdx.y, b = blockIdx.z;
    if (w < tile) return;
    int lane = threadIdx.x;
    __shared__ float4 sj[64];
    __shared__ float aj[64];
    const float4* op = (const float4*)obox + (size_t)b * KC;
    int j0 = w * 64;
    int jl = j0 + lane;
    float4 vj = op[(jl < KC) ? jl : (KC - 1)];
    sj[lane] = vj;
    aj[lane] = __fmul_rn(__fsub_rn(vj.z, vj.x), __fsub_rn(vj.w, vj.y));
    int i = tile * 64 + lane;
    float4 bi = op[(i < KC) ? i : (KC - 1)];
    float ai = __fmul_rn(__fsub_rn(bi.z, bi.x), __fsub_rn(bi.w, bi.y));
    __syncthreads();
    unsigned long long bits = 0;
    int jmax = min(64, KC - j0);
    for (int jj = 0; jj < jmax; ++jj) {
        float4 bj = sj[jj];            // wave-uniform -> LDS broadcast
        float xx1 = fmaxf(bi.x, bj.x), yy1 = fmaxf(bi.y, bj.y);
        float xx2 = fminf(bi.z, bj.z), yy2 = fminf(bi.w, bj.w);
        float ww = fmaxf(__fsub_rn(xx2, xx1), 0.0f);
        float hh = fmaxf(__fsub_rn(yy2, yy1), 0.0f);
        float inter = __fmul_rn(ww, hh);
        float uni = __fsub_rn(__fadd_rn(ai, aj[jj]), inter);
        float iou = __fdiv_rn(inter, fmaxf(uni, 1e-9f));
        bool kp = ((j0 + jj) > i) && (iou > 0.6f);
        bits |= kp ? (1ull << jj) : 0ull;
    }
    if (i >= KC) bits = 0;
    MT[((size_t)b * WORDS + w) * KROWS + i] = bits;
}

// ---------------- K5c: pipelined pull-style greedy scan, early-exit at POSTN kept ------
__global__ __launch_bounds__(64) void k_nms(
        const unsigned long long* __restrict__ MT, const float* __restrict__ ssc,
        const int* __restrict__ slb, const float* __restrict__ sbox, float* __restrict__ out) {
    int b = blockIdx.x, lane = threadIdx.x;
    for (int k = lane; k < POSTN * 5; k += 64) out[(size_t)b * POSTN * 5 + k] = 0.0f;
    for (int k = lane; k < POSTN; k += 64) {
        out[(size_t)NB * POSTN * 5 + b * POSTN + k] = 0.0f;                 // labels
        out[(size_t)NB * POSTN * 5 + NB * POSTN + b * POSTN + k] = 0.0f;    // valid
    }
    const float* sp = ssc + b * KC;
    unsigned long long validV = 0;
    for (int c = 0; c < WORDS; ++c) {
        int i = c * 64 + lane;
        bool f = (i < KC) && (sp[i] > 0.0f);
        unsigned long long m = __ballot(f);
        validV = (lane == c) ? m : validV;
    }
    unsigned long long mybit = 1ull << lane;
    unsigned long long keptV = 0;
    const unsigned long long* Mb = MT + (size_t)b * WORDS * KROWS;

    unsigned long long pv[WORDS];
    pv[0] = Mb[lane];

    int keptTotal = 0;
    for (int t = 0; t < WORDS; ++t) {
        int tn = (t + 1 < WORDS) ? (t + 1) : t;
        const unsigned long long* cp = Mb + (size_t)tn * KROWS + lane;
        unsigned long long nv[WORDS];
        #pragma unroll
        for (int c = 0; c < WORDS; ++c) {
            int cc = (c <= tn) ? c : 0;
            nv[c] = cp[(size_t)cc * 64];
        }
        __builtin_amdgcn_sched_barrier(0);    // loads stay above; compute below

        unsigned long long D = pv[t];
        unsigned long long acc = 0;
        #pragma unroll
        for (int c = 0; c < WORDS; ++c) {
            if (c < t) {
                unsigned long long kc = readlane64(keptV, c);
                if (kc & mybit) acc |= pv[c];
            }
        }
        #pragma unroll
        for (int s = 1; s < 64; s <<= 1) acc |= __shfl_xor(acc, s, 64);

        unsigned long long validT = readlane64(validV, t);
        unsigned long long rem = acc;
        unsigned long long sup = __ballot(D != 0ull) & validT;
        unsigned long long todoS = sup;
        while (todoS) {
            int r = __builtin_ctzll(todoS);
            todoS &= todoS - 1;
            if (!((rem >> r) & 1ull)) {
                unsigned long long Dr = readlane64(D, r);
                rem |= Dr;
                todoS &= ~Dr;
            }
        }
        unsigned long long kept = validT & ~rem;
        keptV = (lane == t) ? kept : keptV;

        keptTotal += (int)__popcll(kept);      // kept is wave-uniform
        if (keptTotal >= POSTN) break;         // first POSTN kept fully determined

        #pragma unroll
        for (int c = 0; c < WORDS; ++c) pv[c] = nv[c];
    }

    int base = 0;
    for (int c = 0; c < WORDS && base < POSTN; ++c) {
        unsigned long long kw = readlane64(keptV, c);
        bool f = (kw & mybit) != 0ull;
        int rank = base + __popcll(kw & (mybit - 1ull));
        if (f && rank < POSTN) {
            int i = c * 64 + lane;
            int src = b * KC + i;
            float* o5 = out + ((size_t)b * POSTN + rank) * 5;
            o5[0] = sbox[src * 4 + 0]; o5[1] = sbox[src * 4 + 1];
            o5[2] = sbox[src * 4 + 2]; o5[3] = sbox[src * 4 + 3];
            o5[4] = ssc[src];
            out[(size_t)NB * POSTN * 5 + b * POSTN + rank] = (float)slb[src];
            out[(size_t)NB * POSTN * 5 + NB * POSTN + b * POSTN + rank] = 1.0f;
        }
        base += __popcll(kw);
    }
}

// ---------------- launch ----------------
extern "C" void kernel_launch(void* const* d_in, const int* in_sizes, int n_in,
                              void* d_out, int out_size, void* d_ws, size_t ws_size,
                              hipStream_t stream) {
    const float *loc[5], *cls[5], *box[5], *ctr[5];
    for (int l = 0; l < 5; ++l) {
        loc[l] = (const float*)d_in[l * 4 + 0];
        cls[l] = (const float*)d_in[l * 4 + 1];
        box[l] = (const float*)d_in[l * 4 + 2];
        ctr[l] = (const float*)d_in[l * 4 + 3];
    }
    char* ws = (char*)d_ws;
    unsigned* hist = (unsigned*)(ws + OFF_HIST);
    unsigned* cnt  = (unsigned*)(ws + OFF_CNT);
    Cand* cand     = (Cand*)(ws + OFF_CAND);
    float* cbox    = (float*)(ws + OFF_CBOX);
    float* csc     = (float*)(ws + OFF_CSC);
    int*   clb     = (int*)(ws + OFF_CLB);
    float* ssc     = (float*)(ws + OFF_SSC);
    int*   slb     = (int*)(ws + OFF_SLB);
    float* sbox    = (float*)(ws + OFF_SBOX);
    float* obox    = (float*)(ws + OFF_OBOX);
    unsigned long long* MT = (unsigned long long*)(ws + OFF_M);
    float* sct     = (float*)(ws + OFF_SCT);
    unsigned short* gmx = (unsigned short*)(ws + OFF_GMX);
    unsigned* tvs  = (unsigned*)(ws + OFF_TV);
    unsigned* gcount = (unsigned*)(ws + OFF_GCNT);
    unsigned* glist  = (unsigned*)(ws + OFF_GL);
    float* out = (float*)d_out;

    int zn = (int)(OFF_CAND / 4);
    int initBlocks = (max(zn, SCTN) + THREADS - 1) / THREADS;
    k_init<<<initBlocks, THREADS, 0, stream>>>(
        ctr[0], ctr[1], ctr[2], ctr[3], ctr[4], sct, (unsigned*)ws, zn, gcount);
    k_hist<<<dim3(CHUNKS, NB), THREADS, 0, stream>>>(
        cls[0], cls[1], cls[2], cls[3], cls[4], sct, gmx, hist);
    k_thresh<<<NPAIR, THREADS, 0, stream>>>(hist, gmx, tvs, gcount, glist);
    k_collect<<<4096, THREADS, 0, stream>>>(
        cls[0], cls[1], cls[2], cls[3], cls[4], sct, tvs, gcount, glist, cand, cnt);
    k_select<<<NPAIR, THREADS, 0, stream>>>(
        cand, cnt,
        loc[0], loc[1], loc[2], loc[3], loc[4],
        box[0], box[1], box[2], box[3], box[4],
        cbox, csc, clb);
    k_sortimg<<<NB, SORTT, 0, stream>>>(csc, clb, cbox, ssc, slb, sbox, obox);
    k_iou<<<dim3(WORDS, WORDS, NB), 64, 0, stream>>>(obox, MT);
    k_nms<<<NB, 64, 0, stream>>>(MT, ssc, slb, sbox, out);
}

// Round 3
// 280.550 us; speedup vs baseline: 1.6229x; 1.6229x over previous
//
#include <hip/hip_runtime.h>
#include <math.h>

#define THREADS 256
#define SORTT 1024

// ---------------- problem constants (fixed by reference setup) ----------------
constexpr int NLEV  = 5;
constexpr int NB    = 16;     // batch
constexpr int NC    = 80;     // classes (label = c+1)
constexpr int TOPN  = 300;
constexpr int KC    = NLEV * TOPN;   // 1500 candidates per image
constexpr int KROWS = 1536;          // padded rows for NMS bitmask
constexpr int WORDS = 24;            // 1536 / 64
constexpr int POSTN = 100;
constexpr int CAP   = 4096;          // per-(b,level) candidate pool
constexpr int NBINS = 2048;          // score-histogram bins over [0.25, 1.0)
constexpr int NPAIR = NLEV * NB;     // 80

constexpr int HW0 = 12800, HW1 = 3200, HW2 = 800, HW3 = 208, HW4 = 56;
constexpr int CH0 = 63, CH1 = 16, CH2 = 4, CH3 = 2, CH4 = 1;  // 16384-elem chunks per (b,level)
constexpr int CHUNKS = CH0 + CH1 + CH2 + CH3 + CH4;           // 86

// sigmoid(ctr) precompute: per-level bases into sct[] (floats), layout [li][b][hw]
constexpr int SCTB0 = 0;
constexpr int SCTB1 = 204800;
constexpr int SCTB2 = 256000;
constexpr int SCTB3 = 268800;
constexpr int SCTB4 = 272128;
constexpr int SCTN  = 273024;

// group-max skip list: 256-element groups, layout [li][b][g] (u16)
constexpr int GPL0 = 4000, GPL1 = 1000, GPL2 = 250, GPL3 = 65, GPL4 = 18;
constexpr int GMXB0 = 0;
constexpr int GMXB1 = GMXB0 + NB * GPL0;
constexpr int GMXB2 = GMXB1 + NB * GPL1;
constexpr int GMXB3 = GMXB2 + NB * GPL2;
constexpr int GMXB4 = GMXB3 + NB * GPL3;
constexpr int GMXN  = GMXB4 + NB * GPL4;

constexpr int GLSTRIDE = 4096;   // per-pid group-list capacity (max GPL0=4000 fits)
constexpr int BPP = 16;          // k_collect blocks per pid

// ---------------- workspace layout ----------------
constexpr size_t align256(size_t x) { return (x + 255) & ~(size_t)255; }
constexpr size_t OFF_HIST = 0;
constexpr size_t OFF_CNT  = OFF_HIST + (size_t)NPAIR * NBINS * 4;
constexpr size_t OFF_CAND = align256(OFF_CNT + (size_t)NPAIR * 4);
constexpr size_t OFF_CBOX = align256(OFF_CAND + (size_t)NPAIR * CAP * 8);
constexpr size_t OFF_CSC  = align256(OFF_CBOX + (size_t)NB * KC * 4 * 4);
constexpr size_t OFF_CLB  = align256(OFF_CSC  + (size_t)NB * KC * 4);
constexpr size_t OFF_SSC  = align256(OFF_CLB  + (size_t)NB * KC * 4);
constexpr size_t OFF_SLB  = align256(OFF_SSC  + (size_t)NB * KC * 4);
constexpr size_t OFF_SBOX = align256(OFF_SLB  + (size_t)NB * KC * 4);
constexpr size_t OFF_OBOX = align256(OFF_SBOX + (size_t)NB * KC * 4 * 4);
constexpr size_t OFF_M    = align256(OFF_OBOX + (size_t)NB * KC * 4 * 4);
constexpr size_t OFF_SCT  = align256(OFF_M + (size_t)NB * KROWS * WORDS * 8);
constexpr size_t OFF_GMX  = align256(OFF_SCT + (size_t)SCTN * 4);
constexpr size_t OFF_TV   = align256(OFF_GMX + (size_t)GMXN * 2);      // NPAIR thresholds (u32)
constexpr size_t OFF_GCNT = align256(OFF_TV + (size_t)NPAIR * 4);      // NPAIR list counts (u32)
constexpr size_t OFF_GL   = align256(OFF_GCNT + (size_t)NPAIR * 4);    // NPAIR * GLSTRIDE u16
// total ~16.6 MB

struct Cand { float s; int i; };

// ---------------- helpers ----------------
__device__ __forceinline__ float sigm(float x) { return 1.0f / (1.0f + expf(-x)); }

// fast sigmoid (hw v_exp_f32 + v_rcp_f32, <=~4 ulp). Used ONLY for the histogram /
// skip-list (threshold selection): |approx key - exact key| <= 1 bin, compensated
// by collecting key >= TA-1 and gating groups by gmx+1 >= Tv. Collect/select use
// the exact sigm() so the final output is bit-identical.
__device__ __forceinline__ float sigf(float x) {
#if __has_builtin(__builtin_amdgcn_exp2f) && __has_builtin(__builtin_amdgcn_rcpf)
    float e = __builtin_amdgcn_exp2f(__fmul_rn(x, -1.44269504088896340736f));
    return __builtin_amdgcn_rcpf(__fadd_rn(1.0f, e));
#else
    return 1.0f / (1.0f + __expf(-x));
#endif
}

// monotone key over score in (0,1): 2048 bins over [0.25,1.0), everything below -> bin 0
__device__ __forceinline__ unsigned scoreKey(float s) {
    unsigned b = __float_as_uint(s);
    unsigned k = (b < 0x3E800000u) ? 0u : ((b - 0x3E800000u) >> 13);
    return (k > 2047u) ? 2047u : k;
}

__device__ __forceinline__ unsigned long long readlane64(unsigned long long v, int l) {
    unsigned lo = (unsigned)__builtin_amdgcn_readlane((int)(unsigned)(v & 0xffffffffull), l);
    unsigned hi = (unsigned)__builtin_amdgcn_readlane((int)(unsigned)(v >> 32), l);
    return ((unsigned long long)hi << 32) | lo;
}

__device__ void bitonicShared(float* ss, int* si, int N) {
    for (int k = 2; k <= N; k <<= 1) {
        for (int j = k >> 1; j > 0; j >>= 1) {
            __syncthreads();
            for (int i = threadIdx.x; i < N; i += blockDim.x) {
                int ixj = i ^ j;
                if (ixj > i) {
                    float s1 = ss[i], s2 = ss[ixj];
                    int a1 = si[i], a2 = si[ixj];
                    bool bef = (s1 > s2) || (s1 == s2 && a1 < a2);   // desc, idx asc
                    bool up = ((i & k) == 0);
                    if (up ? !bef : bef) { ss[i] = s2; ss[ixj] = s1; si[i] = a2; si[ixj] = a1; }
                }
            }
        }
    }
    __syncthreads();
}

// ---------------- K0: fused zero (hist+cnt) + sigmoid(ctr) precompute ----------------
__global__ __launch_bounds__(THREADS) void k_init(
        const float* t0, const float* t1, const float* t2, const float* t3, const float* t4,
        float* __restrict__ sct, unsigned* __restrict__ zp, int zn) {
    int i = blockIdx.x * THREADS + threadIdx.x;
    if (i < zn) zp[i] = 0;
    if (i < SCTN) {
        float x;
        if (i < SCTB1)      x = t0[i - SCTB0];
        else if (i < SCTB2) x = t1[i - SCTB1];
        else if (i < SCTB3) x = t2[i - SCTB2];
        else if (i < SCTB4) x = t3[i - SCTB3];
        else                x = t4[i - SCTB4];
        sct[i] = sigm(x);   // exact: same formula as reference sigmoid usage
    }
}

// ---------------- K1: approx histogram + per-256-group max approx key ----------------
template<int HW, int SCTB, int GPL, int GMXB>
__device__ __forceinline__ void histChunkV(int chunkLocal, int b,
        const float* __restrict__ cls, const float* __restrict__ sct,
        unsigned short* __restrict__ gmx, unsigned* __restrict__ h) {
    constexpr int NE = HW * NC;
    const float* cp = cls + (size_t)b * NE;
    const float* tb = sct + SCTB + b * HW;
    unsigned short* gp = gmx + GMXB + (size_t)b * GPL;
    int w = threadIdx.x >> 6, lane = threadIdx.x & 63;
    int half = lane >> 5, hlane = lane & 31;
    for (int bi = w; bi < 32; bi += 4) {
        int ebase = (chunkLocal * 32 + bi) * 512;
        if (ebase >= NE) break;
        int e = ebase + lane * 8;
        int kmax = 0;
        if (e < NE) {   // NE%8==0 -> e<NE implies e+7<NE
            int c = e / HW; int hwb = e - c * HW;
            float4 xa = *(const float4*)(cp + e);
            float4 xb = *(const float4*)(cp + e + 4);
            float4 ta = *(const float4*)(tb + hwb);
            float4 tc = *(const float4*)(tb + hwb + 4);
            float xs[8] = {xa.x, xa.y, xa.z, xa.w, xb.x, xb.y, xb.z, xb.w};
            float ts[8] = {ta.x, ta.y, ta.z, ta.w, tc.x, tc.y, tc.z, tc.w};
            #pragma unroll
            for (int q = 0; q < 8; ++q) {
                float scls = sigf(xs[q]);                // FAST sigmoid (approx key)
                float s = __fmul_rn(scls, ts[q]);
                unsigned key = scoreKey(s);
                if (key) atomicAdd(&h[key], 1u);
                kmax = max(kmax, (int)key);
            }
        }
        #pragma unroll
        for (int sh = 1; sh < 32; sh <<= 1) kmax = max(kmax, __shfl_xor(kmax, sh, 64));
        int g = (ebase >> 8) + half;
        if (hlane == 0 && g * 256 < NE) gp[g] = (unsigned short)kmax;
    }
}

__global__ __launch_bounds__(THREADS) void k_hist(
        const float* c0, const float* c1, const float* c2, const float* c3, const float* c4,
        const float* __restrict__ sct, unsigned short* __restrict__ gmx, unsigned* ghist) {
    __shared__ unsigned h[NBINS];
    for (int k = threadIdx.x; k < NBINS; k += THREADS) h[k] = 0;
    __syncthreads();
    int cx = blockIdx.x, b = blockIdx.y;
    int li;
    if (cx < CH0)                 { histChunkV<HW0,SCTB0,GPL0,GMXB0>(cx, b, c0, sct, gmx, h); li = 0; }
    else if (cx < CH0+CH1)        { histChunkV<HW1,SCTB1,GPL1,GMXB1>(cx-CH0, b, c1, sct, gmx, h); li = 1; }
    else if (cx < CH0+CH1+CH2)    { histChunkV<HW2,SCTB2,GPL2,GMXB2>(cx-CH0-CH1, b, c2, sct, gmx, h); li = 2; }
    else if (cx < CH0+CH1+CH2+CH3){ histChunkV<HW3,SCTB3,GPL3,GMXB3>(cx-CH0-CH1-CH2, b, c3, sct, gmx, h); li = 3; }
    else                          { histChunkV<HW4,SCTB4,GPL4,GMXB4>(cx-CH0-CH1-CH2-CH3, b, c4, sct, gmx, h); li = 4; }
    __syncthreads();
    unsigned* gp = ghist + (size_t)(li * NB + b) * NBINS;
    for (int k = threadIdx.x; k < NBINS; k += THREADS) {
        unsigned v = h[k];
        if (v) atomicAdd(&gp[k], v);
    }
}

// ---------------- K2: per-(li,b) threshold + per-pid passing-group list ----------
// One block per pid. Computes Tv (identical math), then compacts this pid's passing
// groups into its OWN u16 list via an LDS counter (no global atomics at all).
// List order is arbitrary; downstream selection is order-independent (exact
// comparator on (score, encoded idx)).
__global__ __launch_bounds__(THREADS) void k_thresh(
        const unsigned* __restrict__ ghist, const unsigned short* __restrict__ gmx,
        unsigned* __restrict__ tvs, unsigned* __restrict__ gcntP,
        unsigned short* __restrict__ glistP) {
    __shared__ unsigned seg[THREADS];
    __shared__ unsigned shTv, lofs;
    int pid = blockIdx.x;
    int li = pid >> 4, b = pid & 15;
    const unsigned* h = ghist + (size_t)pid * NBINS;
    constexpr int SB = NBINS / THREADS;   // 8
    unsigned s = 0;
    for (int k = 0; k < SB; ++k) s += h[threadIdx.x * SB + k];
    seg[threadIdx.x] = s;
    __syncthreads();
    if (threadIdx.x == 0) {
        unsigned acc = 0; unsigned TA = 0;
        int t = THREADS - 1;
        for (; t >= 0; --t) {
            if (acc + seg[t] >= (unsigned)TOPN) break;
            acc += seg[t];
        }
        if (t >= 0) {
            int lo = t * SB;
            int bin = lo + SB - 1;
            for (; bin >= lo; --bin) { acc += h[bin]; if (acc >= (unsigned)TOPN) break; }
            TA = (unsigned)max(bin, lo);
        }
        unsigned Tv = (TA >= 1) ? (TA - 1) : 0;   // 0 => degenerate fallback
        shTv = Tv;
        tvs[pid] = Tv;
        lofs = 0;
    }
    __syncthreads();
    unsigned Tv = shTv;
    int GPL, GMXB;
    switch (li) {
        case 0: GPL = GPL0; GMXB = GMXB0; break;
        case 1: GPL = GPL1; GMXB = GMXB1; break;
        case 2: GPL = GPL2; GMXB = GMXB2; break;
        case 3: GPL = GPL3; GMXB = GMXB3; break;
        default: GPL = GPL4; GMXB = GMXB4; break;
    }
    const unsigned short* gp = gmx + GMXB + (size_t)b * GPL;
    unsigned short* gl = glistP + (size_t)pid * GLSTRIDE;
    for (int g0 = 0; g0 < GPL; g0 += THREADS) {
        int g = g0 + (int)threadIdx.x;
        bool ok = (g < GPL);
        if (ok && Tv) ok = ((unsigned)gp[g] + 1u >= Tv);   // gmx is max APPROX key: +1 slack
        unsigned long long m = __ballot(ok);
        int nW = __popcll(m);
        if (nW) {
            unsigned wb = 0;
            if ((threadIdx.x & 63) == 0) wb = atomicAdd(&lofs, (unsigned)nW);  // LDS atomic
            wb = (unsigned)__builtin_amdgcn_readfirstlane((int)wb);
            if (ok) {
                unsigned slot = wb + (unsigned)__popcll(m & ((1ull << (threadIdx.x & 63)) - 1ull));
                gl[slot] = (unsigned short)g;   // slot < GPL <= GLSTRIDE always
            }
        }
    }
    __syncthreads();
    if (threadIdx.x == 0) gcntP[pid] = lofs;
}

// ---------------- K3: per-pid list-driven compaction (round-1 inner machinery) ----
// Each block owns a contiguous slice of its pid's group list. GB-deep batched loads
// for MLP, LDS staging buffer, ONE global atomic per block (fixes the round-2
// 50K-atomic storm on 80 hot addresses).
constexpr int LBUF = 1024;
constexpr int GB = 8;

template<int HW, int SCTB>
__device__ __forceinline__ void collectRange(int b, int pid, unsigned Tv,
        unsigned lo, unsigned hi, const unsigned short* __restrict__ gl,
        const float* __restrict__ cls, const float* __restrict__ sct,
        Cand* __restrict__ cd, unsigned* __restrict__ cnt,
        Cand* __restrict__ lbuf, unsigned* __restrict__ lcnt) {
    constexpr int NE = HW * NC;
    const float* cp = cls + (size_t)b * NE;
    const float* tb = sct + SCTB + b * HW;
    for (unsigned base = lo; base < hi; base += GB) {
        float xv[GB], tv[GB];
        int ev[GB];
        bool okv[GB];
        #pragma unroll
        for (int q = 0; q < GB; ++q) {
            unsigned gi = base + q;
            int g = gl[(gi < hi) ? gi : (hi - 1)];   // hi >= 1 guaranteed by caller
            int e = g * 256 + (int)threadIdx.x;
            bool ok = (gi < hi) && (e < NE);
            e = ok ? e : 0;
            int c = e / HW; int hw = e - c * HW;
            xv[q] = cp[e];
            tv[q] = tb[hw];
            ev[q] = e;
            okv[q] = ok;
        }
        __builtin_amdgcn_sched_barrier(0);   // keep the 2*GB loads batched above the uses
        #pragma unroll
        for (int q = 0; q < GB; ++q) {
            float scls = sigm(xv[q]);        // EXACT sigmoid for stored score
            float s = __fmul_rn(scls, tv[q]);
            unsigned key = scoreKey(s);
            bool take = okv[q] && (Tv ? (key >= Tv) : (scls > 0.05f));
            if (take) {
                int e = ev[q];
                int c = e / HW; int hw = e - c * HW;
                unsigned slot = atomicAdd(lcnt, 1u);
                if (slot < (unsigned)LBUF) { lbuf[slot].s = s; lbuf[slot].i = hw * NC + c; }
                else {
                    unsigned gs = atomicAdd(&cnt[pid], 1u);   // rare fallback
                    if (gs < (unsigned)CAP) { cd[gs].s = s; cd[gs].i = hw * NC + c; }
                }
            }
        }
    }
}

__global__ __launch_bounds__(THREADS) void k_collect(
        const float* c0, const float* c1, const float* c2, const float* c3, const float* c4,
        const float* __restrict__ sct, const unsigned* __restrict__ tvs,
        const unsigned* __restrict__ gcntP, const unsigned short* __restrict__ glistP,
        Cand* cand, unsigned* cnt) {
    __shared__ Cand lbuf[LBUF];
    __shared__ unsigned lcnt, gbase;
    if (threadIdx.x == 0) lcnt = 0;
    __syncthreads();
    int pid = blockIdx.y;
    int li = pid >> 4, b = pid & 15;
    unsigned Tv = tvs[pid];
    unsigned n = gcntP[pid];
    unsigned per = (n + BPP - 1) / BPP;
    unsigned lo = blockIdx.x * per;
    unsigned hi = min(n, lo + per);
    const unsigned short* gl = glistP + (size_t)pid * GLSTRIDE;
    Cand* cd = cand + (size_t)pid * CAP;
    if (lo < hi) {
        switch (li) {
            case 0: collectRange<HW0,SCTB0>(b, pid, Tv, lo, hi, gl, c0, sct, cd, cnt, lbuf, &lcnt); break;
            case 1: collectRange<HW1,SCTB1>(b, pid, Tv, lo, hi, gl, c1, sct, cd, cnt, lbuf, &lcnt); break;
            case 2: collectRange<HW2,SCTB2>(b, pid, Tv, lo, hi, gl, c2, sct, cd, cnt, lbuf, &lcnt); break;
            case 3: collectRange<HW3,SCTB3>(b, pid, Tv, lo, hi, gl, c3, sct, cd, cnt, lbuf, &lcnt); break;
            default: collectRange<HW4,SCTB4>(b, pid, Tv, lo, hi, gl, c4, sct, cd, cnt, lbuf, &lcnt); break;
        }
    }
    __syncthreads();
    unsigned nl = lcnt; if (nl > (unsigned)LBUF) nl = LBUF;
    if (threadIdx.x == 0) gbase = nl ? atomicAdd(&cnt[pid], nl) : 0u;
    __syncthreads();
    for (unsigned i = threadIdx.x; i < nl; i += THREADS) {
        unsigned s = gbase + i;
        if (s < (unsigned)CAP) cd[s] = lbuf[i];
    }
}

// ---------------- K4: exact top-300 per (b,level) + decode (round-1 bitonic) ----------
__global__ __launch_bounds__(THREADS) void k_select(
        const Cand* __restrict__ candAll, const unsigned* __restrict__ cntAll,
        const float* l0, const float* l1, const float* l2, const float* l3, const float* l4,
        const float* b0, const float* b1, const float* b2, const float* b3, const float* b4,
        float* __restrict__ cbox, float* __restrict__ csc, int* __restrict__ clb) {
    __shared__ float ss[CAP];
    __shared__ int si[CAP];
    int pid = blockIdx.x;
    int li = pid / NB, b = pid - li * NB;
    int n = (int)min(cntAll[pid], (unsigned)CAP);
    const Cand* cd = candAll + (size_t)pid * CAP;
    int N = 2; while (N < n) N <<= 1;
    for (int k = threadIdx.x; k < N; k += THREADS) {
        if (k < n) { ss[k] = cd[k].s; si[k] = cd[k].i; }
        else       { ss[k] = -INFINITY; si[k] = 0x40000000 + k; }
    }
    __syncthreads();
    bitonicShared(ss, si, N);

    const float* locp; const float* boxp; int HW;
    switch (li) {
        case 0: locp = l0; boxp = b0; HW = HW0; break;
        case 1: locp = l1; boxp = b1; HW = HW1; break;
        case 2: locp = l2; boxp = b2; HW = HW2; break;
        case 3: locp = l3; boxp = b3; HW = HW3; break;
        default: locp = l4; boxp = b4; HW = HW4; break;
    }
    for (int j = threadIdx.x; j < TOPN; j += THREADS) {
        int cidx = b * KC + li * TOPN + j;
        bool ok = (j < n);
        float s = ok ? ss[j] : -INFINITY;
        ok = ok && (s > 0.0f);
        if (ok) {
            int idx = si[j];
            int hw = idx / NC, c = idx - hw * NC;
            float lx = locp[hw * 2 + 0], ly = locp[hw * 2 + 1];
            const float* bp = boxp + (size_t)b * 4 * HW + hw;
            float bl = bp[0], bt = bp[HW], br = bp[2 * HW], bb = bp[3 * HW];
            float x1 = fminf(fmaxf(__fsub_rn(lx, bl), 0.0f), 1023.0f);
            float y1 = fminf(fmaxf(__fsub_rn(ly, bt), 0.0f),  799.0f);
            float x2 = fminf(fmaxf(__fadd_rn(lx, br), 0.0f), 1023.0f);
            float y2 = fminf(fmaxf(__fadd_rn(ly, bb), 0.0f),  799.0f);
            cbox[cidx * 4 + 0] = x1; cbox[cidx * 4 + 1] = y1;
            cbox[cidx * 4 + 2] = x2; cbox[cidx * 4 + 3] = y2;
            csc[cidx] = sqrtf(fmaxf(s, 1e-12f));
            clb[cidx] = c + 1;
        } else {
            cbox[cidx * 4 + 0] = 0.0f; cbox[cidx * 4 + 1] = 0.0f;
            cbox[cidx * 4 + 2] = 0.0f; cbox[cidx * 4 + 3] = 0.0f;
            csc[cidx] = -INFINITY;
            clb[cidx] = 0;
        }
    }
}

// ---------------- K5a: per-image sort by score desc (round-1 bitonic, 1024 threads) ----
__global__ __launch_bounds__(SORTT) void k_sortimg(
        const float* __restrict__ csc, const int* __restrict__ clb, const float* __restrict__ cbox,
        float* __restrict__ ssc, int* __restrict__ slb, float* __restrict__ sbox, float* __restrict__ obox) {
    int b = blockIdx.x;
    __shared__ float ss[2048];
    __shared__ int si[2048];
    for (int k = threadIdx.x; k < 2048; k += SORTT) {
        if (k < KC) { ss[k] = csc[b * KC + k]; si[k] = k; }
        else        { ss[k] = -INFINITY; si[k] = 0x40000000 + k; }
    }
    __syncthreads();
    bitonicShared(ss, si, 2048);
    for (int k = threadIdx.x; k < KC; k += SORTT) {
        int sl = si[k];                 // all 1500 real entries sort before pads
        int src = b * KC + sl;
        int dst = b * KC + k;
        float sc = ss[k];
        int lab = clb[src];
        ssc[dst] = sc; slb[dst] = lab;
        float off = __fmul_rn((float)lab, 1025.0f);   // offset = max(800,1024)+1
        #pragma unroll
        for (int q = 0; q < 4; ++q) {
            float v = cbox[src * 4 + q];
            sbox[dst * 4 + q] = v;
            obox[dst * 4 + q] = __fadd_rn(v, off);
        }
    }
}

// ---------------- K5b: suppression bitmask (iou > 0.6 && j > i) ----------------
__global__ __launch_bounds__(64) void k_iou(const float* __restrict__ obox,
                                            unsigned long long* __restrict__ MT) {
    int w = blockIdx.x, tile = blockIdx.y, b = blockIdx.z;
    if (w < tile) return;
    int lane = threadIdx.x;
    __shared__ float4 sj[64];
    __shared__ float aj[64];
    const float4* op = (const float4*)obox + (size_t)b * KC;
    int j0 = w * 64;
    int jl = j0 + lane;
    float4 vj = op[(jl < KC) ? jl : (KC - 1)];
    sj[lane] = vj;
    aj[lane] = __fmul_rn(__fsub_rn(vj.z, vj.x), __fsub_rn(vj.w, vj.y));
    int i = tile * 64 + lane;
    float4 bi = op[(i < KC) ? i : (KC - 1)];
    float ai = __fmul_rn(__fsub_rn(bi.z, bi.x), __fsub_rn(bi.w, bi.y));
    __syncthreads();
    unsigned long long bits = 0;
    int jmax = min(64, KC - j0);
    for (int jj = 0; jj < jmax; ++jj) {
        float4 bj = sj[jj];            // wave-uniform -> LDS broadcast
        float xx1 = fmaxf(bi.x, bj.x), yy1 = fmaxf(bi.y, bj.y);
        float xx2 = fminf(bi.z, bj.z), yy2 = fminf(bi.w, bj.w);
        float ww = fmaxf(__fsub_rn(xx2, xx1), 0.0f);
        float hh = fmaxf(__fsub_rn(yy2, yy1), 0.0f);
        float inter = __fmul_rn(ww, hh);
        float uni = __fsub_rn(__fadd_rn(ai, aj[jj]), inter);
        float iou = __fdiv_rn(inter, fmaxf(uni, 1e-9f));
        bool kp = ((j0 + jj) > i) && (iou > 0.6f);
        bits |= kp ? (1ull << jj) : 0ull;
    }
    if (i >= KC) bits = 0;
    MT[((size_t)b * WORDS + w) * KROWS + i] = bits;
}

// ---------------- K5c: pipelined pull-style greedy scan, early-exit at POSTN kept ------
__global__ __launch_bounds__(64) void k_nms(
        const unsigned long long* __restrict__ MT, const float* __restrict__ ssc,
        const int* __restrict__ slb, const float* __restrict__ sbox, float* __restrict__ out) {
    int b = blockIdx.x, lane = threadIdx.x;
    for (int k = lane; k < POSTN * 5; k += 64) out[(size_t)b * POSTN * 5 + k] = 0.0f;
    for (int k = lane; k < POSTN; k += 64) {
        out[(size_t)NB * POSTN * 5 + b * POSTN + k] = 0.0f;                 // labels
        out[(size_t)NB * POSTN * 5 + NB * POSTN + b * POSTN + k] = 0.0f;    // valid
    }
    const float* sp = ssc + b * KC;
    unsigned long long validV = 0;
    for (int c = 0; c < WORDS; ++c) {
        int i = c * 64 + lane;
        bool f = (i < KC) && (sp[i] > 0.0f);
        unsigned long long m = __ballot(f);
        validV = (lane == c) ? m : validV;
    }
    unsigned long long mybit = 1ull << lane;
    unsigned long long keptV = 0;
    const unsigned long long* Mb = MT + (size_t)b * WORDS * KROWS;

    unsigned long long pv[WORDS];
    pv[0] = Mb[lane];

    int keptTotal = 0;
    for (int t = 0; t < WORDS; ++t) {
        int tn = (t + 1 < WORDS) ? (t + 1) : t;
        const unsigned long long* cp = Mb + (size_t)tn * KROWS + lane;
        unsigned long long nv[WORDS];
        #pragma unroll
        for (int c = 0; c < WORDS; ++c) {
            int cc = (c <= tn) ? c : 0;
            nv[c] = cp[(size_t)cc * 64];
        }
        __builtin_amdgcn_sched_barrier(0);    // loads stay above; compute below

        unsigned long long D = pv[t];
        unsigned long long acc = 0;
        #pragma unroll
        for (int c = 0; c < WORDS; ++c) {
            if (c < t) {
                unsigned long long kc = readlane64(keptV, c);
                if (kc & mybit) acc |= pv[c];
            }
        }
        #pragma unroll
        for (int s = 1; s < 64; s <<= 1) acc |= __shfl_xor(acc, s, 64);

        unsigned long long validT = readlane64(validV, t);
        unsigned long long rem = acc;
        unsigned long long sup = __ballot(D != 0ull) & validT;
        unsigned long long todoS = sup;
        while (todoS) {
            int r = __builtin_ctzll(todoS);
            todoS &= todoS - 1;
            if (!((rem >> r) & 1ull)) {
                unsigned long long Dr = readlane64(D, r);
                rem |= Dr;
                todoS &= ~Dr;
            }
        }
        unsigned long long kept = validT & ~rem;
        keptV = (lane == t) ? kept : keptV;

        keptTotal += (int)__popcll(kept);      // kept is wave-uniform
        if (keptTotal >= POSTN) break;         // first POSTN kept fully determined

        #pragma unroll
        for (int c = 0; c < WORDS; ++c) pv[c] = nv[c];
    }

    int base = 0;
    for (int c = 0; c < WORDS && base < POSTN; ++c) {
        unsigned long long kw = readlane64(keptV, c);
        bool f = (kw & mybit) != 0ull;
        int rank = base + __popcll(kw & (mybit - 1ull));
        if (f && rank < POSTN) {
            int i = c * 64 + lane;
            int src = b * KC + i;
            float* o5 = out + ((size_t)b * POSTN + rank) * 5;
            o5[0] = sbox[src * 4 + 0]; o5[1] = sbox[src * 4 + 1];
            o5[2] = sbox[src * 4 + 2]; o5[3] = sbox[src * 4 + 3];
            o5[4] = ssc[src];
            out[(size_t)NB * POSTN * 5 + b * POSTN + rank] = (float)slb[src];
            out[(size_t)NB * POSTN * 5 + NB * POSTN + b * POSTN + rank] = 1.0f;
        }
        base += __popcll(kw);
    }
}

// ---------------- launch ----------------
extern "C" void kernel_launch(void* const* d_in, const int* in_sizes, int n_in,
                              void* d_out, int out_size, void* d_ws, size_t ws_size,
                              hipStream_t stream) {
    const float *loc[5], *cls[5], *box[5], *ctr[5];
    for (int l = 0; l < 5; ++l) {
        loc[l] = (const float*)d_in[l * 4 + 0];
        cls[l] = (const float*)d_in[l * 4 + 1];
        box[l] = (const float*)d_in[l * 4 + 2];
        ctr[l] = (const float*)d_in[l * 4 + 3];
    }
    char* ws = (char*)d_ws;
    unsigned* hist = (unsigned*)(ws + OFF_HIST);
    unsigned* cnt  = (unsigned*)(ws + OFF_CNT);
    Cand* cand     = (Cand*)(ws + OFF_CAND);
    float* cbox    = (float*)(ws + OFF_CBOX);
    float* csc     = (float*)(ws + OFF_CSC);
    int*   clb     = (int*)(ws + OFF_CLB);
    float* ssc     = (float*)(ws + OFF_SSC);
    int*   slb     = (int*)(ws + OFF_SLB);
    float* sbox    = (float*)(ws + OFF_SBOX);
    float* obox    = (float*)(ws + OFF_OBOX);
    unsigned long long* MT = (unsigned long long*)(ws + OFF_M);
    float* sct     = (float*)(ws + OFF_SCT);
    unsigned short* gmx = (unsigned short*)(ws + OFF_GMX);
    unsigned* tvs  = (unsigned*)(ws + OFF_TV);
    unsigned* gcntP = (unsigned*)(ws + OFF_GCNT);
    unsigned short* glistP = (unsigned short*)(ws + OFF_GL);
    float* out = (float*)d_out;

    int zn = (int)(OFF_CAND / 4);
    int initBlocks = (max(zn, SCTN) + THREADS - 1) / THREADS;
    k_init<<<initBlocks, THREADS, 0, stream>>>(
        ctr[0], ctr[1], ctr[2], ctr[3], ctr[4], sct, (unsigned*)ws, zn);
    k_hist<<<dim3(CHUNKS, NB), THREADS, 0, stream>>>(
        cls[0], cls[1], cls[2], cls[3], cls[4], sct, gmx, hist);
    k_thresh<<<NPAIR, THREADS, 0, stream>>>(hist, gmx, tvs, gcntP, glistP);
    k_collect<<<dim3(BPP, NPAIR), THREADS, 0, stream>>>(
        cls[0], cls[1], cls[2], cls[3], cls[4], sct, tvs, gcntP, glistP, cand, cnt);
    k_select<<<NPAIR, THREADS, 0, stream>>>(
        cand, cnt,
        loc[0], loc[1], loc[2], loc[3], loc[4],
        box[0], box[1], box[2], box[3], box[4],
        cbox, csc, clb);
    k_sortimg<<<NB, SORTT, 0, stream>>>(csc, clb, cbox, ssc, slb, sbox, obox);
    k_iou<<<dim3(WORDS, WORDS, NB), 64, 0, stream>>>(obox, MT);
    k_nms<<<NB, 64, 0, stream>>>(MT, ssc, slb, sbox, out);
}

// Round 4
// 247.847 us; speedup vs baseline: 1.8371x; 1.1320x over previous
//
#include <hip/hip_runtime.h>
#include <math.h>

#define THREADS 256

// ---------------- problem constants (fixed by reference setup) ----------------
constexpr int NLEV  = 5;
constexpr int NB    = 16;     // batch
constexpr int NC    = 80;     // classes (label = c+1)
constexpr int TOPN  = 300;
constexpr int KC    = NLEV * TOPN;   // 1500 candidates per image
constexpr int KROWS = 1536;          // padded rows for NMS bitmask
constexpr int WORDS = 24;            // 1536 / 64
constexpr int NTRI  = WORDS * (WORDS + 1) / 2;   // 300 lower-triangle tiles
constexpr int POSTN = 100;
constexpr int CAP   = 4096;          // per-(b,level) candidate pool
constexpr int NBINS = 2048;          // score-histogram bins over [0.25, 1.0)
constexpr int NPAIR = NLEV * NB;     // 80

constexpr int HW0 = 12800, HW1 = 3200, HW2 = 800, HW3 = 208, HW4 = 56;
constexpr int CH0 = 63, CH1 = 16, CH2 = 4, CH3 = 2, CH4 = 1;  // 16384-elem chunks per (b,level)
constexpr int CHUNKS = CH0 + CH1 + CH2 + CH3 + CH4;           // 86

// sigmoid(ctr) precompute: per-level bases into sct[] (floats), layout [li][b][hw]
constexpr int SCTB0 = 0;
constexpr int SCTB1 = 204800;
constexpr int SCTB2 = 256000;
constexpr int SCTB3 = 268800;
constexpr int SCTB4 = 272128;
constexpr int SCTN  = 273024;

// group-max skip list: 256-element groups, layout [li][b][g] (u16)
constexpr int GPL0 = 4000, GPL1 = 1000, GPL2 = 250, GPL3 = 65, GPL4 = 18;
constexpr int GMXB0 = 0;
constexpr int GMXB1 = GMXB0 + NB * GPL0;
constexpr int GMXB2 = GMXB1 + NB * GPL1;
constexpr int GMXB3 = GMXB2 + NB * GPL2;
constexpr int GMXB4 = GMXB3 + NB * GPL3;
constexpr int GMXN  = GMXB4 + NB * GPL4;

constexpr int GLSTRIDE = 4096;   // per-pid group-list capacity (max GPL0=4000 fits)
constexpr int BPP = 16;          // k_collect blocks per pid

// histogram floor per level: big levels (top-300 of >=64K elems) always threshold
// far above s=0.5 (bin 1024) -> skip ~90% of LDS atomics. Small levels keep floor 1.
constexpr int HF_BIG = 1024, HF_SMALL = 1;

// ---------------- workspace layout ----------------
constexpr size_t align256(size_t x) { return (x + 255) & ~(size_t)255; }
constexpr size_t OFF_HIST = 0;
constexpr size_t OFF_CNT  = OFF_HIST + (size_t)NPAIR * NBINS * 4;
constexpr size_t OFF_CAND = align256(OFF_CNT + (size_t)NPAIR * 4);
constexpr size_t OFF_CBOX = align256(OFF_CAND + (size_t)NPAIR * CAP * 8);
constexpr size_t OFF_CSC  = align256(OFF_CBOX + (size_t)NB * KC * 4 * 4);
constexpr size_t OFF_CLB  = align256(OFF_CSC  + (size_t)NB * KC * 4);
constexpr size_t OFF_SSC  = align256(OFF_CLB  + (size_t)NB * KC * 4);
constexpr size_t OFF_SLB  = align256(OFF_SSC  + (size_t)NB * KC * 4);
constexpr size_t OFF_SBOX = align256(OFF_SLB  + (size_t)NB * KC * 4);
constexpr size_t OFF_OBOX = align256(OFF_SBOX + (size_t)NB * KC * 4 * 4);
constexpr size_t OFF_M    = align256(OFF_OBOX + (size_t)NB * KC * 4 * 4);
constexpr size_t OFF_SCT  = align256(OFF_M + (size_t)NB * KROWS * WORDS * 8);
constexpr size_t OFF_GMX  = align256(OFF_SCT + (size_t)SCTN * 4);
constexpr size_t OFF_TV   = align256(OFF_GMX + (size_t)GMXN * 2);      // NPAIR thresholds (u32)
constexpr size_t OFF_GCNT = align256(OFF_TV + (size_t)NPAIR * 4);      // NPAIR list counts (u32)
constexpr size_t OFF_GL   = align256(OFF_GCNT + (size_t)NPAIR * 4);    // NPAIR * GLSTRIDE u16
// total ~16.6 MB

struct Cand { float s; int i; };

// ---------------- helpers ----------------
__device__ __forceinline__ float sigm(float x) { return 1.0f / (1.0f + expf(-x)); }

// fast sigmoid (hw v_exp_f32 + v_rcp_f32, <=~4 ulp). Used ONLY for the histogram /
// skip-list (threshold selection). Collect/select use exact sigm() -> bit-identical.
__device__ __forceinline__ float sigf(float x) {
#if __has_builtin(__builtin_amdgcn_exp2f) && __has_builtin(__builtin_amdgcn_rcpf)
    float e = __builtin_amdgcn_exp2f(__fmul_rn(x, -1.44269504088896340736f));
    return __builtin_amdgcn_rcpf(__fadd_rn(1.0f, e));
#else
    return 1.0f / (1.0f + __expf(-x));
#endif
}

// monotone key over score in (0,1): 2048 bins over [0.25,1.0), everything below -> bin 0
__device__ __forceinline__ unsigned scoreKey(float s) {
    unsigned b = __float_as_uint(s);
    unsigned k = (b < 0x3E800000u) ? 0u : ((b - 0x3E800000u) >> 13);
    return (k > 2047u) ? 2047u : k;
}

__device__ __forceinline__ unsigned long long readlane64(unsigned long long v, int l) {
    unsigned lo = (unsigned)__builtin_amdgcn_readlane((int)(unsigned)(v & 0xffffffffull), l);
    unsigned hi = (unsigned)__builtin_amdgcn_readlane((int)(unsigned)(v >> 32), l);
    return ((unsigned long long)hi << 32) | lo;
}

__device__ void bitonicShared(float* ss, int* si, int N) {
    for (int k = 2; k <= N; k <<= 1) {
        for (int j = k >> 1; j > 0; j >>= 1) {
            __syncthreads();
            for (int i = threadIdx.x; i < N; i += blockDim.x) {
                int ixj = i ^ j;
                if (ixj > i) {
                    float s1 = ss[i], s2 = ss[ixj];
                    int a1 = si[i], a2 = si[ixj];
                    bool bef = (s1 > s2) || (s1 == s2 && a1 < a2);   // desc, idx asc
                    bool up = ((i & k) == 0);
                    if (up ? !bef : bef) { ss[i] = s2; ss[ixj] = s1; si[i] = a2; si[ixj] = a1; }
                }
            }
        }
    }
    __syncthreads();
}

// ---------------- K0: fused zero (hist+cnt) + sigmoid(ctr) precompute ----------------
__global__ __launch_bounds__(THREADS) void k_init(
        const float* t0, const float* t1, const float* t2, const float* t3, const float* t4,
        float* __restrict__ sct, unsigned* __restrict__ zp, int zn) {
    int i = blockIdx.x * THREADS + threadIdx.x;
    if (i < zn) zp[i] = 0;
    if (i < SCTN) {
        float x;
        if (i < SCTB1)      x = t0[i - SCTB0];
        else if (i < SCTB2) x = t1[i - SCTB1];
        else if (i < SCTB3) x = t2[i - SCTB2];
        else if (i < SCTB4) x = t3[i - SCTB3];
        else                x = t4[i - SCTB4];
        sct[i] = sigm(x);   // exact: same formula as reference sigmoid usage
    }
}

// ---------------- K1: approx histogram + per-256-group max approx key ----------------
template<int HW, int SCTB, int GPL, int GMXB, int HF>
__device__ __forceinline__ void histChunkV(int chunkLocal, int b,
        const float* __restrict__ cls, const float* __restrict__ sct,
        unsigned short* __restrict__ gmx, unsigned* __restrict__ h) {
    constexpr int NE = HW * NC;
    const float* cp = cls + (size_t)b * NE;
    const float* tb = sct + SCTB + b * HW;
    unsigned short* gp = gmx + GMXB + (size_t)b * GPL;
    int w = threadIdx.x >> 6, lane = threadIdx.x & 63;
    int half = lane >> 5, hlane = lane & 31;
    for (int bi = w; bi < 32; bi += 4) {
        int ebase = (chunkLocal * 32 + bi) * 512;
        if (ebase >= NE) break;
        int e = ebase + lane * 8;
        int kmax = 0;
        if (e < NE) {   // NE%8==0 -> e<NE implies e+7<NE
            int c = e / HW; int hwb = e - c * HW;
            float4 xa = *(const float4*)(cp + e);
            float4 xb = *(const float4*)(cp + e + 4);
            float4 ta = *(const float4*)(tb + hwb);
            float4 tc = *(const float4*)(tb + hwb + 4);
            float xs[8] = {xa.x, xa.y, xa.z, xa.w, xb.x, xb.y, xb.z, xb.w};
            float ts[8] = {ta.x, ta.y, ta.z, ta.w, tc.x, tc.y, tc.z, tc.w};
            #pragma unroll
            for (int q = 0; q < 8; ++q) {
                float scls = sigf(xs[q]);                // FAST sigmoid (approx key)
                float s = __fmul_rn(scls, ts[q]);
                unsigned key = scoreKey(s);
                if (key >= (unsigned)HF) atomicAdd(&h[key], 1u);   // floor kills dead-bin atomics
                kmax = max(kmax, (int)key);
            }
        }
        #pragma unroll
        for (int sh = 1; sh < 32; sh <<= 1) kmax = max(kmax, __shfl_xor(kmax, sh, 64));
        int g = (ebase >> 8) + half;
        if (hlane == 0 && g * 256 < NE) gp[g] = (unsigned short)kmax;
    }
}

__global__ __launch_bounds__(THREADS) void k_hist(
        const float* c0, const float* c1, const float* c2, const float* c3, const float* c4,
        const float* __restrict__ sct, unsigned short* __restrict__ gmx, unsigned* ghist) {
    __shared__ unsigned h[NBINS];
    for (int k = threadIdx.x; k < NBINS; k += THREADS) h[k] = 0;
    __syncthreads();
    int cx = blockIdx.x, b = blockIdx.y;
    int li;
    if (cx < CH0)                 { histChunkV<HW0,SCTB0,GPL0,GMXB0,HF_BIG>(cx, b, c0, sct, gmx, h); li = 0; }
    else if (cx < CH0+CH1)        { histChunkV<HW1,SCTB1,GPL1,GMXB1,HF_BIG>(cx-CH0, b, c1, sct, gmx, h); li = 1; }
    else if (cx < CH0+CH1+CH2)    { histChunkV<HW2,SCTB2,GPL2,GMXB2,HF_BIG>(cx-CH0-CH1, b, c2, sct, gmx, h); li = 2; }
    else if (cx < CH0+CH1+CH2+CH3){ histChunkV<HW3,SCTB3,GPL3,GMXB3,HF_SMALL>(cx-CH0-CH1-CH2, b, c3, sct, gmx, h); li = 3; }
    else                          { histChunkV<HW4,SCTB4,GPL4,GMXB4,HF_SMALL>(cx-CH0-CH1-CH2-CH3, b, c4, sct, gmx, h); li = 4; }
    __syncthreads();
    unsigned* gp = ghist + (size_t)(li * NB + b) * NBINS;
    for (int k = threadIdx.x; k < NBINS; k += THREADS) {
        unsigned v = h[k];
        if (v) atomicAdd(&gp[k], v);
    }
}

// ---------------- K2: per-(li,b) threshold + per-pid passing-group list ----------
__global__ __launch_bounds__(THREADS) void k_thresh(
        const unsigned* __restrict__ ghist, const unsigned short* __restrict__ gmx,
        unsigned* __restrict__ tvs, unsigned* __restrict__ gcntP,
        unsigned short* __restrict__ glistP) {
    __shared__ unsigned seg[THREADS];
    __shared__ unsigned shTv, lofs;
    int pid = blockIdx.x;
    int li = pid >> 4, b = pid & 15;
    const unsigned* h = ghist + (size_t)pid * NBINS;
    constexpr int SB = NBINS / THREADS;   // 8
    unsigned s = 0;
    for (int k = 0; k < SB; ++k) s += h[threadIdx.x * SB + k];
    seg[threadIdx.x] = s;
    __syncthreads();
    if (threadIdx.x == 0) {
        unsigned acc = 0; unsigned TA = 0;
        int t = THREADS - 1;
        for (; t >= 0; --t) {
            if (acc + seg[t] >= (unsigned)TOPN) break;
            acc += seg[t];
        }
        if (t >= 0) {
            int lo = t * SB;
            int bin = lo + SB - 1;
            for (; bin >= lo; --bin) { acc += h[bin]; if (acc >= (unsigned)TOPN) break; }
            TA = (unsigned)max(bin, lo);
        }
        unsigned Tv = (TA >= 1) ? (TA - 1) : 0;   // 0 => degenerate fallback
        shTv = Tv;
        tvs[pid] = Tv;
        lofs = 0;
    }
    __syncthreads();
    unsigned Tv = shTv;
    int GPL, GMXB;
    switch (li) {
        case 0: GPL = GPL0; GMXB = GMXB0; break;
        case 1: GPL = GPL1; GMXB = GMXB1; break;
        case 2: GPL = GPL2; GMXB = GMXB2; break;
        case 3: GPL = GPL3; GMXB = GMXB3; break;
        default: GPL = GPL4; GMXB = GMXB4; break;
    }
    const unsigned short* gp = gmx + GMXB + (size_t)b * GPL;
    unsigned short* gl = glistP + (size_t)pid * GLSTRIDE;
    for (int g0 = 0; g0 < GPL; g0 += THREADS) {
        int g = g0 + (int)threadIdx.x;
        bool ok = (g < GPL);
        if (ok && Tv) ok = ((unsigned)gp[g] + 1u >= Tv);   // gmx is max APPROX key: +1 slack
        unsigned long long m = __ballot(ok);
        int nW = __popcll(m);
        if (nW) {
            unsigned wb = 0;
            if ((threadIdx.x & 63) == 0) wb = atomicAdd(&lofs, (unsigned)nW);  // LDS atomic
            wb = (unsigned)__builtin_amdgcn_readfirstlane((int)wb);
            if (ok) {
                unsigned slot = wb + (unsigned)__popcll(m & ((1ull << (threadIdx.x & 63)) - 1ull));
                gl[slot] = (unsigned short)g;   // slot < GPL <= GLSTRIDE always
            }
        }
    }
    __syncthreads();
    if (threadIdx.x == 0) gcntP[pid] = lofs;
}

// ---------------- K3: per-pid list-driven compaction ----------
constexpr int LBUF = 1024;
constexpr int GB = 8;

template<int HW, int SCTB>
__device__ __forceinline__ void collectRange(int b, int pid, unsigned Tv,
        unsigned lo, unsigned hi, const unsigned short* __restrict__ gl,
        const float* __restrict__ cls, const float* __restrict__ sct,
        Cand* __restrict__ cd, unsigned* __restrict__ cnt,
        Cand* __restrict__ lbuf, unsigned* __restrict__ lcnt) {
    constexpr int NE = HW * NC;
    const float* cp = cls + (size_t)b * NE;
    const float* tb = sct + SCTB + b * HW;
    for (unsigned base = lo; base < hi; base += GB) {
        float xv[GB], tv[GB];
        int ev[GB];
        bool okv[GB];
        #pragma unroll
        for (int q = 0; q < GB; ++q) {
            unsigned gi = base + q;
            int g = gl[(gi < hi) ? gi : (hi - 1)];   // hi >= 1 guaranteed by caller
            int e = g * 256 + (int)threadIdx.x;
            bool ok = (gi < hi) && (e < NE);
            e = ok ? e : 0;
            int c = e / HW; int hw = e - c * HW;
            xv[q] = cp[e];
            tv[q] = tb[hw];
            ev[q] = e;
            okv[q] = ok;
        }
        __builtin_amdgcn_sched_barrier(0);   // keep the 2*GB loads batched above the uses
        #pragma unroll
        for (int q = 0; q < GB; ++q) {
            float scls = sigm(xv[q]);        // EXACT sigmoid for stored score
            float s = __fmul_rn(scls, tv[q]);
            unsigned key = scoreKey(s);
            bool take = okv[q] && (Tv ? (key >= Tv) : (scls > 0.05f));
            if (take) {
                int e = ev[q];
                int c = e / HW; int hw = e - c * HW;
                unsigned slot = atomicAdd(lcnt, 1u);
                if (slot < (unsigned)LBUF) { lbuf[slot].s = s; lbuf[slot].i = hw * NC + c; }
                else {
                    unsigned gs = atomicAdd(&cnt[pid], 1u);   // rare fallback
                    if (gs < (unsigned)CAP) { cd[gs].s = s; cd[gs].i = hw * NC + c; }
                }
            }
        }
    }
}

__global__ __launch_bounds__(THREADS) void k_collect(
        const float* c0, const float* c1, const float* c2, const float* c3, const float* c4,
        const float* __restrict__ sct, const unsigned* __restrict__ tvs,
        const unsigned* __restrict__ gcntP, const unsigned short* __restrict__ glistP,
        Cand* cand, unsigned* cnt) {
    __shared__ Cand lbuf[LBUF];
    __shared__ unsigned lcnt, gbase;
    if (threadIdx.x == 0) lcnt = 0;
    __syncthreads();
    int pid = blockIdx.y;
    int li = pid >> 4, b = pid & 15;
    unsigned Tv = tvs[pid];
    unsigned n = gcntP[pid];
    unsigned per = (n + BPP - 1) / BPP;
    unsigned lo = blockIdx.x * per;
    unsigned hi = min(n, lo + per);
    const unsigned short* gl = glistP + (size_t)pid * GLSTRIDE;
    Cand* cd = cand + (size_t)pid * CAP;
    if (lo < hi) {
        switch (li) {
            case 0: collectRange<HW0,SCTB0>(b, pid, Tv, lo, hi, gl, c0, sct, cd, cnt, lbuf, &lcnt); break;
            case 1: collectRange<HW1,SCTB1>(b, pid, Tv, lo, hi, gl, c1, sct, cd, cnt, lbuf, &lcnt); break;
            case 2: collectRange<HW2,SCTB2>(b, pid, Tv, lo, hi, gl, c2, sct, cd, cnt, lbuf, &lcnt); break;
            case 3: collectRange<HW3,SCTB3>(b, pid, Tv, lo, hi, gl, c3, sct, cd, cnt, lbuf, &lcnt); break;
            default: collectRange<HW4,SCTB4>(b, pid, Tv, lo, hi, gl, c4, sct, cd, cnt, lbuf, &lcnt); break;
        }
    }
    __syncthreads();
    unsigned nl = lcnt; if (nl > (unsigned)LBUF) nl = LBUF;
    if (threadIdx.x == 0) gbase = nl ? atomicAdd(&cnt[pid], nl) : 0u;
    __syncthreads();
    for (unsigned i = threadIdx.x; i < nl; i += THREADS) {
        unsigned s = gbase + i;
        if (s < (unsigned)CAP) cd[s] = lbuf[i];
    }
}

// ---------------- K4: exact top-300 per (b,level) + decode (bitonic) ----------
__global__ __launch_bounds__(THREADS) void k_select(
        const Cand* __restrict__ candAll, const unsigned* __restrict__ cntAll,
        const float* l0, const float* l1, const float* l2, const float* l3, const float* l4,
        const float* b0, const float* b1, const float* b2, const float* b3, const float* b4,
        float* __restrict__ cbox, float* __restrict__ csc, int* __restrict__ clb) {
    __shared__ float ss[CAP];
    __shared__ int si[CAP];
    int pid = blockIdx.x;
    int li = pid / NB, b = pid - li * NB;
    int n = (int)min(cntAll[pid], (unsigned)CAP);
    const Cand* cd = candAll + (size_t)pid * CAP;
    int N = 2; while (N < n) N <<= 1;
    for (int k = threadIdx.x; k < N; k += THREADS) {
        if (k < n) { ss[k] = cd[k].s; si[k] = cd[k].i; }
        else       { ss[k] = -INFINITY; si[k] = 0x40000000 + k; }
    }
    __syncthreads();
    bitonicShared(ss, si, N);

    const float* locp; const float* boxp; int HW;
    switch (li) {
        case 0: locp = l0; boxp = b0; HW = HW0; break;
        case 1: locp = l1; boxp = b1; HW = HW1; break;
        case 2: locp = l2; boxp = b2; HW = HW2; break;
        case 3: locp = l3; boxp = b3; HW = HW3; break;
        default: locp = l4; boxp = b4; HW = HW4; break;
    }
    for (int j = threadIdx.x; j < TOPN; j += THREADS) {
        int cidx = b * KC + li * TOPN + j;
        bool ok = (j < n);
        float s = ok ? ss[j] : -INFINITY;
        ok = ok && (s > 0.0f);
        if (ok) {
            int idx = si[j];
            int hw = idx / NC, c = idx - hw * NC;
            float lx = locp[hw * 2 + 0], ly = locp[hw * 2 + 1];
            const float* bp = boxp + (size_t)b * 4 * HW + hw;
            float bl = bp[0], bt = bp[HW], br = bp[2 * HW], bb = bp[3 * HW];
            float x1 = fminf(fmaxf(__fsub_rn(lx, bl), 0.0f), 1023.0f);
            float y1 = fminf(fmaxf(__fsub_rn(ly, bt), 0.0f),  799.0f);
            float x2 = fminf(fmaxf(__fadd_rn(lx, br), 0.0f), 1023.0f);
            float y2 = fminf(fmaxf(__fadd_rn(ly, bb), 0.0f),  799.0f);
            cbox[cidx * 4 + 0] = x1; cbox[cidx * 4 + 1] = y1;
            cbox[cidx * 4 + 2] = x2; cbox[cidx * 4 + 3] = y2;
            csc[cidx] = sqrtf(fmaxf(s, 1e-12f));
            clb[cidx] = c + 1;
        } else {
            cbox[cidx * 4 + 0] = 0.0f; cbox[cidx * 4 + 1] = 0.0f;
            cbox[cidx * 4 + 2] = 0.0f; cbox[cidx * 4 + 3] = 0.0f;
            csc[cidx] = -INFINITY;
            clb[cidx] = 0;
        }
    }
}

// ---------------- K5a: 5-way merge by rank (replaces full-image bitonic sort) --------
// Each level's 300-entry slice of csc is already sorted (score desc, idx asc) by
// k_select. Global rank of element j in level li:
//   rank = j  +  Σ_{l'<li} #{s' >= s}  +  Σ_{l'>li} #{s' > s}
// The ge/gt split reproduces JAX's stable argsort(-s) tie order (level-major,
// position-minor) EXACTLY -> permutation identical to the old bitonic's.
__global__ __launch_bounds__(THREADS) void k_merge(
        const float* __restrict__ csc, const int* __restrict__ clb, const float* __restrict__ cbox,
        float* __restrict__ ssc, int* __restrict__ slb, float* __restrict__ sbox,
        float* __restrict__ obox) {
    int li = blockIdx.x, b = blockIdx.y;
    __shared__ float ss[KC];
    for (int k = threadIdx.x; k < KC; k += THREADS) ss[k] = csc[b * KC + k];
    __syncthreads();
    for (int j = threadIdx.x; j < TOPN; j += THREADS) {
        int k = li * TOPN + j;
        float s = ss[k];
        int rank = j;
        #pragma unroll
        for (int l = 0; l < NLEV; ++l) {
            if (l == li) continue;                 // wave-uniform branch
            const float* seg = ss + l * TOPN;
            int lo = 0, hi = TOPN;
            if (l < li) {
                while (lo < hi) { int m = (lo + hi) >> 1; if (seg[m] >= s) lo = m + 1; else hi = m; }
            } else {
                while (lo < hi) { int m = (lo + hi) >> 1; if (seg[m] >  s) lo = m + 1; else hi = m; }
            }
            rank += lo;
        }
        int src = b * KC + k, dst = b * KC + rank;
        int lab = clb[src];
        ssc[dst] = s; slb[dst] = lab;
        float off = __fmul_rn((float)lab, 1025.0f);   // offset = max(800,1024)+1
        float4 v = *(const float4*)&cbox[(size_t)src * 4];
        *(float4*)&sbox[(size_t)dst * 4] = v;
        float4 o;
        o.x = __fadd_rn(v.x, off); o.y = __fadd_rn(v.y, off);
        o.z = __fadd_rn(v.z, off); o.w = __fadd_rn(v.w, off);
        *(float4*)&obox[(size_t)dst * 4] = o;
    }
}

// ---------------- K5b: suppression bitmask (iou > 0.6 && j > i), triangular grid -----
__global__ __launch_bounds__(64) void k_iou(const float* __restrict__ obox,
                                            unsigned long long* __restrict__ MT) {
    // decode lower-triangle pair index -> (tile, w) with w >= tile
    int t = blockIdx.x, b = blockIdx.y;
    int tile = 0, rem = t;
    while (rem >= WORDS - tile) { rem -= WORDS - tile; ++tile; }
    int w = tile + rem;
    int lane = threadIdx.x;
    __shared__ float4 sj[64];
    __shared__ float aj[64];
    const float4* op = (const float4*)obox + (size_t)b * KC;
    int j0 = w * 64;
    int jl = j0 + lane;
    float4 vj = op[(jl < KC) ? jl : (KC - 1)];
    sj[lane] = vj;
    aj[lane] = __fmul_rn(__fsub_rn(vj.z, vj.x), __fsub_rn(vj.w, vj.y));
    int i = tile * 64 + lane;
    float4 bi = op[(i < KC) ? i : (KC - 1)];
    float ai = __fmul_rn(__fsub_rn(bi.z, bi.x), __fsub_rn(bi.w, bi.y));
    __syncthreads();
    unsigned long long bits = 0;
    int jmax = min(64, KC - j0);
    for (int jj = 0; jj < jmax; ++jj) {
        float4 bj = sj[jj];            // wave-uniform -> LDS broadcast
        float xx1 = fmaxf(bi.x, bj.x), yy1 = fmaxf(bi.y, bj.y);
        float xx2 = fminf(bi.z, bj.z), yy2 = fminf(bi.w, bj.w);
        float ww = fmaxf(__fsub_rn(xx2, xx1), 0.0f);
        float hh = fmaxf(__fsub_rn(yy2, yy1), 0.0f);
        float inter = __fmul_rn(ww, hh);
        float uni = __fsub_rn(__fadd_rn(ai, aj[jj]), inter);
        float iou = __fdiv_rn(inter, fmaxf(uni, 1e-9f));
        bool kp = ((j0 + jj) > i) && (iou > 0.6f);
        bits |= kp ? (1ull << jj) : 0ull;
    }
    if (i >= KC) bits = 0;
    MT[((size_t)b * WORDS + w) * KROWS + i] = bits;
}

// ---------------- K5c: pipelined pull-style greedy scan, early-exit at POSTN kept ------
__global__ __launch_bounds__(64) void k_nms(
        const unsigned long long* __restrict__ MT, const float* __restrict__ ssc,
        const int* __restrict__ slb, const float* __restrict__ sbox, float* __restrict__ out) {
    int b = blockIdx.x, lane = threadIdx.x;
    for (int k = lane; k < POSTN * 5; k += 64) out[(size_t)b * POSTN * 5 + k] = 0.0f;
    for (int k = lane; k < POSTN; k += 64) {
        out[(size_t)NB * POSTN * 5 + b * POSTN + k] = 0.0f;                 // labels
        out[(size_t)NB * POSTN * 5 + NB * POSTN + b * POSTN + k] = 0.0f;    // valid
    }
    const float* sp = ssc + b * KC;
    unsigned long long validV = 0;
    for (int c = 0; c < WORDS; ++c) {
        int i = c * 64 + lane;
        bool f = (i < KC) && (sp[i] > 0.0f);
        unsigned long long m = __ballot(f);
        validV = (lane == c) ? m : validV;
    }
    unsigned long long mybit = 1ull << lane;
    unsigned long long keptV = 0;
    const unsigned long long* Mb = MT + (size_t)b * WORDS * KROWS;

    unsigned long long pv[WORDS];
    pv[0] = Mb[lane];

    int keptTotal = 0;
    for (int t = 0; t < WORDS; ++t) {
        int tn = (t + 1 < WORDS) ? (t + 1) : t;
        const unsigned long long* cp = Mb + (size_t)tn * KROWS + lane;
        unsigned long long nv[WORDS];
        #pragma unroll
        for (int c = 0; c < WORDS; ++c) {
            int cc = (c <= tn) ? c : 0;
            nv[c] = cp[(size_t)cc * 64];
        }
        __builtin_amdgcn_sched_barrier(0);    // loads stay above; compute below

        unsigned long long D = pv[t];
        unsigned long long acc = 0;
        #pragma unroll
        for (int c = 0; c < WORDS; ++c) {
            if (c < t) {
                unsigned long long kc = readlane64(keptV, c);
                if (kc & mybit) acc |= pv[c];
            }
        }
        #pragma unroll
        for (int s = 1; s < 64; s <<= 1) acc |= __shfl_xor(acc, s, 64);

        unsigned long long validT = readlane64(validV, t);
        unsigned long long rem = acc;
        unsigned long long sup = __ballot(D != 0ull) & validT;
        unsigned long long todoS = sup;
        while (todoS) {
            int r = __builtin_ctzll(todoS);
            todoS &= todoS - 1;
            if (!((rem >> r) & 1ull)) {
                unsigned long long Dr = readlane64(D, r);
                rem |= Dr;
                todoS &= ~Dr;
            }
        }
        unsigned long long kept = validT & ~rem;
        keptV = (lane == t) ? kept : keptV;

        keptTotal += (int)__popcll(kept);      // kept is wave-uniform
        if (keptTotal >= POSTN) break;         // first POSTN kept fully determined

        #pragma unroll
        for (int c = 0; c < WORDS; ++c) pv[c] = nv[c];
    }

    int base = 0;
    for (int c = 0; c < WORDS && base < POSTN; ++c) {
        unsigned long long kw = readlane64(keptV, c);
        bool f = (kw & mybit) != 0ull;
        int rank = base + __popcll(kw & (mybit - 1ull));
        if (f && rank < POSTN) {
            int i = c * 64 + lane;
            int src = b * KC + i;
            float* o5 = out + ((size_t)b * POSTN + rank) * 5;
            o5[0] = sbox[src * 4 + 0]; o5[1] = sbox[src * 4 + 1];
            o5[2] = sbox[src * 4 + 2]; o5[3] = sbox[src * 4 + 3];
            o5[4] = ssc[src];
            out[(size_t)NB * POSTN * 5 + b * POSTN + rank] = (float)slb[src];
            out[(size_t)NB * POSTN * 5 + NB * POSTN + b * POSTN + rank] = 1.0f;
        }
        base += __popcll(kw);
    }
}

// ---------------- launch ----------------
extern "C" void kernel_launch(void* const* d_in, const int* in_sizes, int n_in,
                              void* d_out, int out_size, void* d_ws, size_t ws_size,
                              hipStream_t stream) {
    const float *loc[5], *cls[5], *box[5], *ctr[5];
    for (int l = 0; l < 5; ++l) {
        loc[l] = (const float*)d_in[l * 4 + 0];
        cls[l] = (const float*)d_in[l * 4 + 1];
        box[l] = (const float*)d_in[l * 4 + 2];
        ctr[l] = (const float*)d_in[l * 4 + 3];
    }
    char* ws = (char*)d_ws;
    unsigned* hist = (unsigned*)(ws + OFF_HIST);
    unsigned* cnt  = (unsigned*)(ws + OFF_CNT);
    Cand* cand     = (Cand*)(ws + OFF_CAND);
    float* cbox    = (float*)(ws + OFF_CBOX);
    float* csc     = (float*)(ws + OFF_CSC);
    int*   clb     = (int*)(ws + OFF_CLB);
    float* ssc     = (float*)(ws + OFF_SSC);
    int*   slb     = (int*)(ws + OFF_SLB);
    float* sbox    = (float*)(ws + OFF_SBOX);
    float* obox    = (float*)(ws + OFF_OBOX);
    unsigned long long* MT = (unsigned long long*)(ws + OFF_M);
    float* sct     = (float*)(ws + OFF_SCT);
    unsigned short* gmx = (unsigned short*)(ws + OFF_GMX);
    unsigned* tvs  = (unsigned*)(ws + OFF_TV);
    unsigned* gcntP = (unsigned*)(ws + OFF_GCNT);
    unsigned short* glistP = (unsigned short*)(ws + OFF_GL);
    float* out = (float*)d_out;

    int zn = (int)(OFF_CAND / 4);
    int initBlocks = (max(zn, SCTN) + THREADS - 1) / THREADS;
    k_init<<<initBlocks, THREADS, 0, stream>>>(
        ctr[0], ctr[1], ctr[2], ctr[3], ctr[4], sct, (unsigned*)ws, zn);
    k_hist<<<dim3(CHUNKS, NB), THREADS, 0, stream>>>(
        cls[0], cls[1], cls[2], cls[3], cls[4], sct, gmx, hist);
    k_thresh<<<NPAIR, THREADS, 0, stream>>>(hist, gmx, tvs, gcntP, glistP);
    k_collect<<<dim3(BPP, NPAIR), THREADS, 0, stream>>>(
        cls[0], cls[1], cls[2], cls[3], cls[4], sct, tvs, gcntP, glistP, cand, cnt);
    k_select<<<NPAIR, THREADS, 0, stream>>>(
        cand, cnt,
        loc[0], loc[1], loc[2], loc[3], loc[4],
        box[0], box[1], box[2], box[3], box[4],
        cbox, csc, clb);
    k_merge<<<dim3(NLEV, NB), THREADS, 0, stream>>>(csc, clb, cbox, ssc, slb, sbox, obox);
    k_iou<<<dim3(NTRI, NB), 64, 0, stream>>>(obox, MT);
    k_nms<<<NB, 64, 0, stream>>>(MT, ssc, slb, sbox, out);
}

// Round 5
// 240.186 us; speedup vs baseline: 1.8957x; 1.0319x over previous
//
#include <hip/hip_runtime.h>
#include <math.h>

#define THREADS 256

// ---------------- problem constants (fixed by reference setup) ----------------
constexpr int NLEV  = 5;
constexpr int NB    = 16;     // batch
constexpr int NC    = 80;     // classes (label = c+1)
constexpr int TOPN  = 300;
constexpr int KC    = NLEV * TOPN;   // 1500 candidates per image
constexpr int KROWS = 1536;          // padded rows for NMS bitmask
constexpr int WORDS = 24;            // 1536 / 64
constexpr int NTRI  = WORDS * (WORDS + 1) / 2;   // 300 lower-triangle tiles
constexpr int POSTN = 100;
constexpr int CAP   = 4096;          // per-(b,level) candidate pool
constexpr int NBINS = 2048;          // score-histogram bins over [0.25, 1.0)
constexpr int NPAIR = NLEV * NB;     // 80

constexpr int HW0 = 12800, HW1 = 3200, HW2 = 800, HW3 = 208, HW4 = 56;
constexpr int CH0 = 63, CH1 = 16, CH2 = 4, CH3 = 2, CH4 = 1;  // 16384-elem chunks per (b,level)
constexpr int CHUNKS = CH0 + CH1 + CH2 + CH3 + CH4;           // 86

// group-max skip list: 256-element groups, layout [li][b][g] (u16)
constexpr int GPL0 = 4000, GPL1 = 1000, GPL2 = 250, GPL3 = 65, GPL4 = 18;
constexpr int GMXB0 = 0;
constexpr int GMXB1 = GMXB0 + NB * GPL0;
constexpr int GMXB2 = GMXB1 + NB * GPL1;
constexpr int GMXB3 = GMXB2 + NB * GPL2;
constexpr int GMXB4 = GMXB3 + NB * GPL3;
constexpr int GMXN  = GMXB4 + NB * GPL4;

constexpr int BPP = 16;          // k_collect blocks per pid (max slice 4000/16=250 < THREADS)

// histogram floor per level: big levels (top-300 of >=64K elems) always threshold
// far above s=0.5 (bin 1024) -> skip ~90% of LDS atomics. Small levels keep floor 1.
constexpr int HF_BIG = 1024, HF_SMALL = 1;

// ---------------- workspace layout ----------------
constexpr size_t align256(size_t x) { return (x + 255) & ~(size_t)255; }
constexpr size_t OFF_HIST = 0;
constexpr size_t OFF_CNT  = OFF_HIST + (size_t)NPAIR * NBINS * 4;
constexpr size_t OFF_CAND = align256(OFF_CNT + (size_t)NPAIR * 4);
constexpr size_t OFF_CBOX = align256(OFF_CAND + (size_t)NPAIR * CAP * 8);
constexpr size_t OFF_CSC  = align256(OFF_CBOX + (size_t)NB * KC * 4 * 4);
constexpr size_t OFF_CLB  = align256(OFF_CSC  + (size_t)NB * KC * 4);
constexpr size_t OFF_SSC  = align256(OFF_CLB  + (size_t)NB * KC * 4);
constexpr size_t OFF_SLB  = align256(OFF_SSC  + (size_t)NB * KC * 4);
constexpr size_t OFF_SBOX = align256(OFF_SLB  + (size_t)NB * KC * 4);
constexpr size_t OFF_OBOX = align256(OFF_SBOX + (size_t)NB * KC * 4 * 4);
constexpr size_t OFF_M    = align256(OFF_OBOX + (size_t)NB * KC * 4 * 4);
constexpr size_t OFF_GMX  = align256(OFF_M + (size_t)NB * KROWS * WORDS * 8);
// total ~9.7 MB

struct Cand { float s; int i; };

// ---------------- helpers ----------------
__device__ __forceinline__ float sigm(float x) { return 1.0f / (1.0f + expf(-x)); }

// fast sigmoid (hw v_exp_f32 + v_rcp_f32, <=~4 ulp). Used ONLY for the histogram /
// skip-list (threshold selection): combined |approx key - exact key| <= 1 bin
// (bins are 2^13 ulp wide; sigf error is ~4 ulp per factor), compensated by
// Tv = TA-1 and the gmx+1 group gate. Collect/select use exact sigm().
__device__ __forceinline__ float sigf(float x) {
#if __has_builtin(__builtin_amdgcn_exp2f) && __has_builtin(__builtin_amdgcn_rcpf)
    float e = __builtin_amdgcn_exp2f(__fmul_rn(x, -1.44269504088896340736f));
    return __builtin_amdgcn_rcpf(__fadd_rn(1.0f, e));
#else
    return 1.0f / (1.0f + __expf(-x));
#endif
}

// monotone key over score in (0,1): 2048 bins over [0.25,1.0), everything below -> bin 0
__device__ __forceinline__ unsigned scoreKey(float s) {
    unsigned b = __float_as_uint(s);
    unsigned k = (b < 0x3E800000u) ? 0u : ((b - 0x3E800000u) >> 13);
    return (k > 2047u) ? 2047u : k;
}

__device__ __forceinline__ unsigned long long readlane64(unsigned long long v, int l) {
    unsigned lo = (unsigned)__builtin_amdgcn_readlane((int)(unsigned)(v & 0xffffffffull), l);
    unsigned hi = (unsigned)__builtin_amdgcn_readlane((int)(unsigned)(v >> 32), l);
    return ((unsigned long long)hi << 32) | lo;
}

__device__ void bitonicShared(float* ss, int* si, int N) {
    for (int k = 2; k <= N; k <<= 1) {
        for (int j = k >> 1; j > 0; j >>= 1) {
            __syncthreads();
            for (int i = threadIdx.x; i < N; i += blockDim.x) {
                int ixj = i ^ j;
                if (ixj > i) {
                    float s1 = ss[i], s2 = ss[ixj];
                    int a1 = si[i], a2 = si[ixj];
                    bool bef = (s1 > s2) || (s1 == s2 && a1 < a2);   // desc, idx asc
                    bool up = ((i & k) == 0);
                    if (up ? !bef : bef) { ss[i] = s2; ss[ixj] = s1; si[i] = a2; si[ixj] = a1; }
                }
            }
        }
    }
    __syncthreads();
}

// ---------------- K0: zero hist+cnt (sct precompute eliminated; ctr inlined) ---------
__global__ __launch_bounds__(THREADS) void k_zero(unsigned* __restrict__ zp, int zn) {
    int i = blockIdx.x * THREADS + threadIdx.x;
    if (i < zn) zp[i] = 0;
}

// ---------------- K1: approx histogram + per-256-group max approx key ----------------
// sigmoid(ctr) now computed inline with sigf (approx side only; slack covers it).
template<int HW, int GPL, int GMXB, int HF>
__device__ __forceinline__ void histChunkV(int chunkLocal, int b,
        const float* __restrict__ cls, const float* __restrict__ ctr,
        unsigned short* __restrict__ gmx, unsigned* __restrict__ h) {
    constexpr int NE = HW * NC;
    const float* cp = cls + (size_t)b * NE;
    const float* tb = ctr + (size_t)b * HW;
    unsigned short* gp = gmx + GMXB + (size_t)b * GPL;
    int w = threadIdx.x >> 6, lane = threadIdx.x & 63;
    int half = lane >> 5, hlane = lane & 31;
    for (int bi = w; bi < 32; bi += 4) {
        int ebase = (chunkLocal * 32 + bi) * 512;
        if (ebase >= NE) break;
        int e = ebase + lane * 8;
        int kmax = 0;
        if (e < NE) {   // NE%8==0 -> e<NE implies e+7<NE
            int c = e / HW; int hwb = e - c * HW;
            float4 xa = *(const float4*)(cp + e);
            float4 xb = *(const float4*)(cp + e + 4);
            float4 ta = *(const float4*)(tb + hwb);
            float4 tc = *(const float4*)(tb + hwb + 4);
            float xs[8] = {xa.x, xa.y, xa.z, xa.w, xb.x, xb.y, xb.z, xb.w};
            float ts[8] = {ta.x, ta.y, ta.z, ta.w, tc.x, tc.y, tc.z, tc.w};
            #pragma unroll
            for (int q = 0; q < 8; ++q) {
                float scls = sigf(xs[q]);                // FAST sigmoid (approx key)
                float s = __fmul_rn(scls, sigf(ts[q]));  // FAST sigmoid(ctr) inline
                unsigned key = scoreKey(s);
                if (key >= (unsigned)HF) atomicAdd(&h[key], 1u);   // floor kills dead-bin atomics
                kmax = max(kmax, (int)key);
            }
        }
        #pragma unroll
        for (int sh = 1; sh < 32; sh <<= 1) kmax = max(kmax, __shfl_xor(kmax, sh, 64));
        int g = (ebase >> 8) + half;
        if (hlane == 0 && g * 256 < NE) gp[g] = (unsigned short)kmax;
    }
}

__global__ __launch_bounds__(THREADS) void k_hist(
        const float* c0, const float* c1, const float* c2, const float* c3, const float* c4,
        const float* t0, const float* t1, const float* t2, const float* t3, const float* t4,
        unsigned short* __restrict__ gmx, unsigned* ghist) {
    __shared__ unsigned h[NBINS];
    for (int k = threadIdx.x; k < NBINS; k += THREADS) h[k] = 0;
    __syncthreads();
    int cx = blockIdx.x, b = blockIdx.y;
    int li;
    if (cx < CH0)                 { histChunkV<HW0,GPL0,GMXB0,HF_BIG>(cx, b, c0, t0, gmx, h); li = 0; }
    else if (cx < CH0+CH1)        { histChunkV<HW1,GPL1,GMXB1,HF_BIG>(cx-CH0, b, c1, t1, gmx, h); li = 1; }
    else if (cx < CH0+CH1+CH2)    { histChunkV<HW2,GPL2,GMXB2,HF_BIG>(cx-CH0-CH1, b, c2, t2, gmx, h); li = 2; }
    else if (cx < CH0+CH1+CH2+CH3){ histChunkV<HW3,GPL3,GMXB3,HF_SMALL>(cx-CH0-CH1-CH2, b, c3, t3, gmx, h); li = 3; }
    else                          { histChunkV<HW4,GPL4,GMXB4,HF_SMALL>(cx-CH0-CH1-CH2-CH3, b, c4, t4, gmx, h); li = 4; }
    __syncthreads();
    unsigned* gp = ghist + (size_t)(li * NB + b) * NBINS;
    for (int k = threadIdx.x; k < NBINS; k += THREADS) {
        unsigned v = h[k];
        if (v) atomicAdd(&gp[k], v);
    }
}

// ---------------- K2: fused threshold + slice-scan + compaction -----------------------
// Each block (bx, pid): (a) computes Tv from ghist with a PARALLEL suffix scan
// (identical math to the old serial k_thresh — same TA, same Tv; all 16 blocks of a
// pid derive the same value deterministically), (b) scans its static gmx slice,
// ballot-compacts passing groups into LDS, (c) round-1 GB-batched collection with
// LDS staging and ONE global atomic per block. k_thresh launch + glist round-trip gone.
constexpr int LBUF = 1024;
constexpr int GB = 8;

template<int HW>
__device__ __forceinline__ void procList(int b, int pid, unsigned Tv, unsigned n,
        const unsigned short* __restrict__ glist,
        const float* __restrict__ cls, const float* __restrict__ ctr,
        Cand* __restrict__ cd, unsigned* __restrict__ cnt,
        Cand* __restrict__ lbuf, unsigned* __restrict__ lcnt) {
    constexpr int NE = HW * NC;
    const float* cp = cls + (size_t)b * NE;
    const float* tb = ctr + (size_t)b * HW;
    for (unsigned base = 0; base < n; base += GB) {
        float xv[GB], rv[GB];
        int ev[GB];
        bool okv[GB];
        #pragma unroll
        for (int q = 0; q < GB; ++q) {
            unsigned gi = base + q;
            int g = glist[(gi < n) ? gi : (n - 1)];   // n >= 1 guaranteed by caller
            int e = g * 256 + (int)threadIdx.x;
            bool ok = (gi < n) && (e < NE);
            e = ok ? e : 0;
            int c = e / HW; int hw = e - c * HW;
            xv[q] = cp[e];
            rv[q] = tb[hw];
            ev[q] = e;
            okv[q] = ok;
        }
        __builtin_amdgcn_sched_barrier(0);   // keep the 2*GB loads batched above the uses
        #pragma unroll
        for (int q = 0; q < GB; ++q) {
            float scls = sigm(xv[q]);                    // EXACT sigmoid(cls)
            float s = __fmul_rn(scls, sigm(rv[q]));      // EXACT sigmoid(ctr): bit-identical
            unsigned key = scoreKey(s);
            bool take = okv[q] && (Tv ? (key >= Tv) : (scls > 0.05f));
            if (take) {
                int e = ev[q];
                int c = e / HW; int hw = e - c * HW;
                unsigned slot = atomicAdd(lcnt, 1u);
                if (slot < (unsigned)LBUF) { lbuf[slot].s = s; lbuf[slot].i = hw * NC + c; }
                else {
                    unsigned gs = atomicAdd(&cnt[pid], 1u);   // rare fallback
                    if (gs < (unsigned)CAP) { cd[gs].s = s; cd[gs].i = hw * NC + c; }
                }
            }
        }
    }
}

__global__ __launch_bounds__(THREADS) void k_collect(
        const float* c0, const float* c1, const float* c2, const float* c3, const float* c4,
        const float* t0, const float* t1, const float* t2, const float* t3, const float* t4,
        const unsigned* __restrict__ ghist, const unsigned short* __restrict__ gmx,
        Cand* cand, unsigned* cnt) {
    __shared__ unsigned sfx[THREADS];
    __shared__ int tstar;
    __shared__ unsigned shTv;
    __shared__ Cand lbuf[LBUF];
    __shared__ unsigned lcnt, gbase, gcnt;
    __shared__ unsigned short glist[THREADS];
    int tid = (int)threadIdx.x;
    int pid = blockIdx.y;
    int li = pid >> 4, b = pid & 15;
    if (tid == 0) { lcnt = 0; gcnt = 0; tstar = -1; }

    // ---- Tv: parallel suffix-scan over 256 8-bin segments (exact equivalent of the
    // old serial top-down walk: t* = largest t with suffix[t] >= TOPN, then 8-bin scan)
    const unsigned* h = ghist + (size_t)pid * NBINS;
    unsigned s = 0;
    #pragma unroll
    for (int k = 0; k < 8; ++k) s += h[tid * 8 + k];
    sfx[tid] = s;
    for (int d = 1; d < THREADS; d <<= 1) {
        __syncthreads();
        unsigned v = (tid + d < THREADS) ? sfx[tid + d] : 0u;
        __syncthreads();
        sfx[tid] += v;
    }
    __syncthreads();
    if (sfx[tid] >= (unsigned)TOPN && (tid == THREADS - 1 || sfx[tid + 1] < (unsigned)TOPN))
        tstar = tid;   // sfx non-increasing -> unique
    __syncthreads();
    if (tid == 0) {
        unsigned TA = 0;
        int t = tstar;
        if (t >= 0) {
            unsigned acc = (t < THREADS - 1) ? sfx[t + 1] : 0u;
            int lo = t * 8, bin = lo + 7;
            for (; bin >= lo; --bin) { acc += h[bin]; if (acc >= (unsigned)TOPN) break; }
            TA = (unsigned)max(bin, lo);
        }
        shTv = (TA >= 1) ? (TA - 1) : 0u;   // 0 => degenerate fallback
    }
    __syncthreads();
    unsigned Tv = shTv;

    // ---- static gmx slice -> ballot-compacted local group list (single round: per<=250)
    int GPL, GMXB;
    switch (li) {
        case 0: GPL = GPL0; GMXB = GMXB0; break;
        case 1: GPL = GPL1; GMXB = GMXB1; break;
        case 2: GPL = GPL2; GMXB = GMXB2; break;
        case 3: GPL = GPL3; GMXB = GMXB3; break;
        default: GPL = GPL4; GMXB = GMXB4; break;
    }
    const unsigned short* gp = gmx + GMXB + (size_t)b * GPL;
    int per = (GPL + BPP - 1) / BPP;
    int lo = (int)blockIdx.x * per;
    int hi = min(GPL, lo + per);
    {
        int g = lo + tid;
        bool ok = (g < hi);
        if (ok && Tv) ok = ((unsigned)gp[g] + 1u >= Tv);   // gmx is max APPROX key: +1 slack
        unsigned long long m = __ballot(ok);
        int nW = __popcll(m);
        if (nW) {
            unsigned wb = 0;
            if ((tid & 63) == 0) wb = atomicAdd(&gcnt, (unsigned)nW);   // LDS atomic
            wb = (unsigned)__builtin_amdgcn_readfirstlane((int)wb);
            if (ok) glist[wb + (unsigned)__popcll(m & ((1ull << (tid & 63)) - 1ull))] = (unsigned short)g;
        }
    }
    __syncthreads();
    unsigned n = gcnt;
    Cand* cd = cand + (size_t)pid * CAP;
    if (n) {
        switch (li) {
            case 0: procList<HW0>(b, pid, Tv, n, glist, c0, t0, cd, cnt, lbuf, &lcnt); break;
            case 1: procList<HW1>(b, pid, Tv, n, glist, c1, t1, cd, cnt, lbuf, &lcnt); break;
            case 2: procList<HW2>(b, pid, Tv, n, glist, c2, t2, cd, cnt, lbuf, &lcnt); break;
            case 3: procList<HW3>(b, pid, Tv, n, glist, c3, t3, cd, cnt, lbuf, &lcnt); break;
            default: procList<HW4>(b, pid, Tv, n, glist, c4, t4, cd, cnt, lbuf, &lcnt); break;
        }
    }
    __syncthreads();
    unsigned nl = lcnt; if (nl > (unsigned)LBUF) nl = LBUF;
    if (tid == 0) gbase = nl ? atomicAdd(&cnt[pid], nl) : 0u;
    __syncthreads();
    for (unsigned i = tid; i < nl; i += THREADS) {
        unsigned sl = gbase + i;
        if (sl < (unsigned)CAP) cd[sl] = lbuf[i];
    }
}

// ---------------- K4: exact top-300 per (b,level) + decode (bitonic) ----------
__global__ __launch_bounds__(THREADS) void k_select(
        const Cand* __restrict__ candAll, const unsigned* __restrict__ cntAll,
        const float* l0, const float* l1, const float* l2, const float* l3, const float* l4,
        const float* b0, const float* b1, const float* b2, const float* b3, const float* b4,
        float* __restrict__ cbox, float* __restrict__ csc, int* __restrict__ clb) {
    __shared__ float ss[CAP];
    __shared__ int si[CAP];
    int pid = blockIdx.x;
    int li = pid / NB, b = pid - li * NB;
    int n = (int)min(cntAll[pid], (unsigned)CAP);
    const Cand* cd = candAll + (size_t)pid * CAP;
    int N = 2; while (N < n) N <<= 1;
    for (int k = threadIdx.x; k < N; k += THREADS) {
        if (k < n) { ss[k] = cd[k].s; si[k] = cd[k].i; }
        else       { ss[k] = -INFINITY; si[k] = 0x40000000 + k; }
    }
    __syncthreads();
    bitonicShared(ss, si, N);

    const float* locp; const float* boxp; int HW;
    switch (li) {
        case 0: locp = l0; boxp = b0; HW = HW0; break;
        case 1: locp = l1; boxp = b1; HW = HW1; break;
        case 2: locp = l2; boxp = b2; HW = HW2; break;
        case 3: locp = l3; boxp = b3; HW = HW3; break;
        default: locp = l4; boxp = b4; HW = HW4; break;
    }
    for (int j = threadIdx.x; j < TOPN; j += THREADS) {
        int cidx = b * KC + li * TOPN + j;
        bool ok = (j < n);
        float s = ok ? ss[j] : -INFINITY;
        ok = ok && (s > 0.0f);
        if (ok) {
            int idx = si[j];
            int hw = idx / NC, c = idx - hw * NC;
            float lx = locp[hw * 2 + 0], ly = locp[hw * 2 + 1];
            const float* bp = boxp + (size_t)b * 4 * HW + hw;
            float bl = bp[0], bt = bp[HW], br = bp[2 * HW], bb = bp[3 * HW];
            float x1 = fminf(fmaxf(__fsub_rn(lx, bl), 0.0f), 1023.0f);
            float y1 = fminf(fmaxf(__fsub_rn(ly, bt), 0.0f),  799.0f);
            float x2 = fminf(fmaxf(__fadd_rn(lx, br), 0.0f), 1023.0f);
            float y2 = fminf(fmaxf(__fadd_rn(ly, bb), 0.0f),  799.0f);
            cbox[cidx * 4 + 0] = x1; cbox[cidx * 4 + 1] = y1;
            cbox[cidx * 4 + 2] = x2; cbox[cidx * 4 + 3] = y2;
            csc[cidx] = sqrtf(fmaxf(s, 1e-12f));
            clb[cidx] = c + 1;
        } else {
            cbox[cidx * 4 + 0] = 0.0f; cbox[cidx * 4 + 1] = 0.0f;
            cbox[cidx * 4 + 2] = 0.0f; cbox[cidx * 4 + 3] = 0.0f;
            csc[cidx] = -INFINITY;
            clb[cidx] = 0;
        }
    }
}

// ---------------- K5a: 5-way merge by rank (stable, matches argsort(-s) exactly) -----
__global__ __launch_bounds__(THREADS) void k_merge(
        const float* __restrict__ csc, const int* __restrict__ clb, const float* __restrict__ cbox,
        float* __restrict__ ssc, int* __restrict__ slb, float* __restrict__ sbox,
        float* __restrict__ obox) {
    int li = blockIdx.x, b = blockIdx.y;
    __shared__ float ss[KC];
    for (int k = threadIdx.x; k < KC; k += THREADS) ss[k] = csc[b * KC + k];
    __syncthreads();
    for (int j = threadIdx.x; j < TOPN; j += THREADS) {
        int k = li * TOPN + j;
        float s = ss[k];
        int rank = j;
        #pragma unroll
        for (int l = 0; l < NLEV; ++l) {
            if (l == li) continue;                 // wave-uniform branch
            const float* seg = ss + l * TOPN;
            int lo = 0, hi = TOPN;
            if (l < li) {
                while (lo < hi) { int m = (lo + hi) >> 1; if (seg[m] >= s) lo = m + 1; else hi = m; }
            } else {
                while (lo < hi) { int m = (lo + hi) >> 1; if (seg[m] >  s) lo = m + 1; else hi = m; }
            }
            rank += lo;
        }
        int src = b * KC + k, dst = b * KC + rank;
        int lab = clb[src];
        ssc[dst] = s; slb[dst] = lab;
        float off = __fmul_rn((float)lab, 1025.0f);   // offset = max(800,1024)+1
        float4 v = *(const float4*)&cbox[(size_t)src * 4];
        *(float4*)&sbox[(size_t)dst * 4] = v;
        float4 o;
        o.x = __fadd_rn(v.x, off); o.y = __fadd_rn(v.y, off);
        o.z = __fadd_rn(v.z, off); o.w = __fadd_rn(v.w, off);
        *(float4*)&obox[(size_t)dst * 4] = o;
    }
}

// ---------------- K5b: suppression bitmask (iou > 0.6 && j > i), triangular grid -----
__global__ __launch_bounds__(64) void k_iou(const float* __restrict__ obox,
                                            unsigned long long* __restrict__ MT) {
    // decode lower-triangle pair index -> (tile, w) with w >= tile
    int t = blockIdx.x, b = blockIdx.y;
    int tile = 0, rem = t;
    while (rem >= WORDS - tile) { rem -= WORDS - tile; ++tile; }
    int w = tile + rem;
    int lane = threadIdx.x;
    __shared__ float4 sj[64];
    __shared__ float aj[64];
    const float4* op = (const float4*)obox + (size_t)b * KC;
    int j0 = w * 64;
    int jl = j0 + lane;
    float4 vj = op[(jl < KC) ? jl : (KC - 1)];
    sj[lane] = vj;
    aj[lane] = __fmul_rn(__fsub_rn(vj.z, vj.x), __fsub_rn(vj.w, vj.y));
    int i = tile * 64 + lane;
    float4 bi = op[(i < KC) ? i : (KC - 1)];
    float ai = __fmul_rn(__fsub_rn(bi.z, bi.x), __fsub_rn(bi.w, bi.y));
    __syncthreads();
    unsigned long long bits = 0;
    int jmax = min(64, KC - j0);
    for (int jj = 0; jj < jmax; ++jj) {
        float4 bj = sj[jj];            // wave-uniform -> LDS broadcast
        float xx1 = fmaxf(bi.x, bj.x), yy1 = fmaxf(bi.y, bj.y);
        float xx2 = fminf(bi.z, bj.z), yy2 = fminf(bi.w, bj.w);
        float ww = fmaxf(__fsub_rn(xx2, xx1), 0.0f);
        float hh = fmaxf(__fsub_rn(yy2, yy1), 0.0f);
        float inter = __fmul_rn(ww, hh);
        float uni = __fsub_rn(__fadd_rn(ai, aj[jj]), inter);
        float iou = __fdiv_rn(inter, fmaxf(uni, 1e-9f));
        bool kp = ((j0 + jj) > i) && (iou > 0.6f);
        bits |= kp ? (1ull << jj) : 0ull;
    }
    if (i >= KC) bits = 0;
    MT[((size_t)b * WORDS + w) * KROWS + i] = bits;
}

// ---------------- K5c: pipelined pull-style greedy scan, early-exit at POSTN kept ------
__global__ __launch_bounds__(64) void k_nms(
        const unsigned long long* __restrict__ MT, const float* __restrict__ ssc,
        const int* __restrict__ slb, const float* __restrict__ sbox, float* __restrict__ out) {
    int b = blockIdx.x, lane = threadIdx.x;
    for (int k = lane; k < POSTN * 5; k += 64) out[(size_t)b * POSTN * 5 + k] = 0.0f;
    for (int k = lane; k < POSTN; k += 64) {
        out[(size_t)NB * POSTN * 5 + b * POSTN + k] = 0.0f;                 // labels
        out[(size_t)NB * POSTN * 5 + NB * POSTN + b * POSTN + k] = 0.0f;    // valid
    }
    const float* sp = ssc + b * KC;
    unsigned long long validV = 0;
    for (int c = 0; c < WORDS; ++c) {
        int i = c * 64 + lane;
        bool f = (i < KC) && (sp[i] > 0.0f);
        unsigned long long m = __ballot(f);
        validV = (lane == c) ? m : validV;
    }
    unsigned long long mybit = 1ull << lane;
    unsigned long long keptV = 0;
    const unsigned long long* Mb = MT + (size_t)b * WORDS * KROWS;

    unsigned long long pv[WORDS];
    pv[0] = Mb[lane];

    int keptTotal = 0;
    for (int t = 0; t < WORDS; ++t) {
        int tn = (t + 1 < WORDS) ? (t + 1) : t;
        const unsigned long long* cp = Mb + (size_t)tn * KROWS + lane;
        unsigned long long nv[WORDS];
        #pragma unroll
        for (int c = 0; c < WORDS; ++c) {
            int cc = (c <= tn) ? c : 0;
            nv[c] = cp[(size_t)cc * 64];
        }
        __builtin_amdgcn_sched_barrier(0);    // loads stay above; compute below

        unsigned long long D = pv[t];
        unsigned long long acc = 0;
        #pragma unroll
        for (int c = 0; c < WORDS; ++c) {
            if (c < t) {
                unsigned long long kc = readlane64(keptV, c);
                if (kc & mybit) acc |= pv[c];
            }
        }
        #pragma unroll
        for (int s = 1; s < 64; s <<= 1) acc |= __shfl_xor(acc, s, 64);

        unsigned long long validT = readlane64(validV, t);
        unsigned long long rem = acc;
        unsigned long long sup = __ballot(D != 0ull) & validT;
        unsigned long long todoS = sup;
        while (todoS) {
            int r = __builtin_ctzll(todoS);
            todoS &= todoS - 1;
            if (!((rem >> r) & 1ull)) {
                unsigned long long Dr = readlane64(D, r);
                rem |= Dr;
                todoS &= ~Dr;
            }
        }
        unsigned long long kept = validT & ~rem;
        keptV = (lane == t) ? kept : keptV;

        keptTotal += (int)__popcll(kept);      // kept is wave-uniform
        if (keptTotal >= POSTN) break;         // first POSTN kept fully determined

        #pragma unroll
        for (int c = 0; c < WORDS; ++c) pv[c] = nv[c];
    }

    int base = 0;
    for (int c = 0; c < WORDS && base < POSTN; ++c) {
        unsigned long long kw = readlane64(keptV, c);
        bool f = (kw & mybit) != 0ull;
        int rank = base + __popcll(kw & (mybit - 1ull));
        if (f && rank < POSTN) {
            int i = c * 64 + lane;
            int src = b * KC + i;
            float* o5 = out + ((size_t)b * POSTN + rank) * 5;
            o5[0] = sbox[src * 4 + 0]; o5[1] = sbox[src * 4 + 1];
            o5[2] = sbox[src * 4 + 2]; o5[3] = sbox[src * 4 + 3];
            o5[4] = ssc[src];
            out[(size_t)NB * POSTN * 5 + b * POSTN + rank] = (float)slb[src];
            out[(size_t)NB * POSTN * 5 + NB * POSTN + b * POSTN + rank] = 1.0f;
        }
        base += __popcll(kw);
    }
}

// ---------------- launch (7 dispatches, was 8) ----------------
extern "C" void kernel_launch(void* const* d_in, const int* in_sizes, int n_in,
                              void* d_out, int out_size, void* d_ws, size_t ws_size,
                              hipStream_t stream) {
    const float *loc[5], *cls[5], *box[5], *ctr[5];
    for (int l = 0; l < 5; ++l) {
        loc[l] = (const float*)d_in[l * 4 + 0];
        cls[l] = (const float*)d_in[l * 4 + 1];
        box[l] = (const float*)d_in[l * 4 + 2];
        ctr[l] = (const float*)d_in[l * 4 + 3];
    }
    char* ws = (char*)d_ws;
    unsigned* hist = (unsigned*)(ws + OFF_HIST);
    unsigned* cnt  = (unsigned*)(ws + OFF_CNT);
    Cand* cand     = (Cand*)(ws + OFF_CAND);
    float* cbox    = (float*)(ws + OFF_CBOX);
    float* csc     = (float*)(ws + OFF_CSC);
    int*   clb     = (int*)(ws + OFF_CLB);
    float* ssc     = (float*)(ws + OFF_SSC);
    int*   slb     = (int*)(ws + OFF_SLB);
    float* sbox    = (float*)(ws + OFF_SBOX);
    float* obox    = (float*)(ws + OFF_OBOX);
    unsigned long long* MT = (unsigned long long*)(ws + OFF_M);
    unsigned short* gmx = (unsigned short*)(ws + OFF_GMX);
    float* out = (float*)d_out;

    int zn = (int)(OFF_CAND / 4);
    k_zero<<<(zn + THREADS - 1) / THREADS, THREADS, 0, stream>>>((unsigned*)ws, zn);
    k_hist<<<dim3(CHUNKS, NB), THREADS, 0, stream>>>(
        cls[0], cls[1], cls[2], cls[3], cls[4],
        ctr[0], ctr[1], ctr[2], ctr[3], ctr[4], gmx, hist);
    k_collect<<<dim3(BPP, NPAIR), THREADS, 0, stream>>>(
        cls[0], cls[1], cls[2], cls[3], cls[4],
        ctr[0], ctr[1], ctr[2], ctr[3], ctr[4], hist, gmx, cand, cnt);
    k_select<<<NPAIR, THREADS, 0, stream>>>(
        cand, cnt,
        loc[0], loc[1], loc[2], loc[3], loc[4],
        box[0], box[1], box[2], box[3], box[4],
        cbox, csc, clb);
    k_merge<<<dim3(NLEV, NB), THREADS, 0, stream>>>(csc, clb, cbox, ssc, slb, sbox, obox);
    k_iou<<<dim3(NTRI, NB), 64, 0, stream>>>(obox, MT);
    k_nms<<<NB, 64, 0, stream>>>(MT, ssc, slb, sbox, out);
}